// Round 1
// baseline (4266.179 us; speedup 1.0000x reference)
//
#include <hip/hip_runtime.h>
#include <math.h>

// Problem constants (from reference)
#define Bb    2
#define Ss    1024
#define HIDd  2048
#define NHh   16
#define HDd   128
#define SBc   20      // floor(0.02*1024+0.5)
#define SELBc 61      // floor(0.06*1024+0.5)
#define RBc   82      // floor(0.08*1024+0.5)
#define CBc   163     // SB+SELB+RB
#define FFf   0.9f
#define MASKVAL (-3.4028234663852886e38f)
#define NBH   (Bb*NHh)       // 32
#define NROWS (NBH*Ss)       // 32768

// ---------------------------------------------------------------------------
// Generic 64x64-tile fp32 GEMM, 256 threads, 4x4 micro-tile.
// MODE 0: C[m*N+n] plain row-major.
// MODE 1: qkv permute: m=b*S+s, n=h*HD+d  ->  C[((b*NH+h)*S+s)*HD+d]
// ---------------------------------------------------------------------------
template<int MODE>
__global__ __launch_bounds__(256) void gemm64x64(const float* __restrict__ A,
                                                 const float* __restrict__ Bm,
                                                 float* __restrict__ C,
                                                 int M, int N, int K)
{
    __shared__ float As[16][65];   // [k][m], padded
    __shared__ float Bs[16][64];   // [k][n]
    int tid = threadIdx.x;
    int tx = tid & 15, ty = tid >> 4;
    int bm = blockIdx.y * 64, bn = blockIdx.x * 64;
    float acc[4][4] = {};
    for (int k0 = 0; k0 < K; k0 += 16) {
#pragma unroll
        for (int l = 0; l < 4; ++l) {
            int idx = tid + l * 256;
            int r = idx >> 4, c = idx & 15;
            As[c][r] = A[(size_t)(bm + r) * K + k0 + c];
        }
#pragma unroll
        for (int l = 0; l < 4; ++l) {
            int idx = tid + l * 256;
            int r = idx >> 6, c = idx & 63;
            Bs[r][c] = Bm[(size_t)(k0 + r) * N + bn + c];
        }
        __syncthreads();
#pragma unroll
        for (int kk = 0; kk < 16; ++kk) {
            float a[4], b[4];
#pragma unroll
            for (int i = 0; i < 4; ++i) a[i] = As[kk][ty * 4 + i];
#pragma unroll
            for (int j = 0; j < 4; ++j) b[j] = Bs[kk][tx * 4 + j];
#pragma unroll
            for (int i = 0; i < 4; ++i)
#pragma unroll
                for (int j = 0; j < 4; ++j)
                    acc[i][j] = fmaf(a[i], b[j], acc[i][j]);
        }
        __syncthreads();
    }
#pragma unroll
    for (int i = 0; i < 4; ++i) {
        int m = bm + ty * 4 + i;
#pragma unroll
        for (int j = 0; j < 4; ++j) {
            int n = bn + tx * 4 + j;
            if (MODE == 0) {
                C[(size_t)m * N + n] = acc[i][j];
            } else {
                int b_ = m / Ss, s_ = m % Ss;
                int h_ = n / HDd, d_ = n % HDd;
                C[(size_t)((b_ * NHh + h_) * Ss + s_) * HDd + d_] = acc[i][j];
            }
        }
    }
}

// ---------------------------------------------------------------------------
// RoPE, in-place on q and k. One block per (b,h,s), 64 threads (pair d, d+64).
// ---------------------------------------------------------------------------
__global__ __launch_bounds__(64) void rope_qk(float* __restrict__ q, float* __restrict__ k)
{
    int idx = blockIdx.x;          // bh*S + s
    int s = idx % Ss;
    int d = threadIdx.x;           // 0..63
    float inv = powf(10000.0f, -2.0f * (float)d / 128.0f);
    float fr = (float)s * inv;
    float c = cosf(fr), sn = sinf(fr);
    size_t base = (size_t)idx * HDd;
    float q1 = q[base + d], q2 = q[base + d + 64];
    q[base + d]      = q1 * c - q2 * sn;
    q[base + d + 64] = q2 * c + q1 * sn;
    float k1 = k[base + d], k2 = k[base + d + 64];
    k[base + d]      = k1 * c - k2 * sn;
    k[base + d + 64] = k2 * c + k1 * sn;
}

// ---------------------------------------------------------------------------
// attn = q k^T / sqrt(HD), causal-masked to MASKVAL. 64x64 tiles per (b,h).
// ---------------------------------------------------------------------------
__global__ __launch_bounds__(256) void attn_qk(const float* __restrict__ q,
                                               const float* __restrict__ kmat,
                                               float* __restrict__ attn)
{
    int bh = blockIdx.z;
    int bm = blockIdx.y * 64, bn = blockIdx.x * 64;
    float* out = attn + (size_t)bh * Ss * Ss;
    int tid = threadIdx.x, tx = tid & 15, ty = tid >> 4;

    if (blockIdx.x > blockIdx.y) {  // entire tile above diagonal -> masked
#pragma unroll
        for (int i = 0; i < 4; ++i) {
            int sq = bm + ty * 4 + i;
#pragma unroll
            for (int j = 0; j < 4; ++j) {
                int sk = bn + tx * 4 + j;
                out[(size_t)sq * Ss + sk] = MASKVAL;
            }
        }
        return;
    }
    const float* Q  = q    + (size_t)bh * Ss * HDd;
    const float* Kh = kmat + (size_t)bh * Ss * HDd;
    __shared__ float As[16][65], Ks[16][65];
    float acc[4][4] = {};
    for (int k0 = 0; k0 < HDd; k0 += 16) {
#pragma unroll
        for (int l = 0; l < 4; ++l) {
            int idx = tid + l * 256;
            int r = idx >> 4, c = idx & 15;
            As[c][r] = Q[(size_t)(bm + r) * HDd + k0 + c];
            Ks[c][r] = Kh[(size_t)(bn + r) * HDd + k0 + c];
        }
        __syncthreads();
#pragma unroll
        for (int kk = 0; kk < 16; ++kk) {
            float a[4], b[4];
#pragma unroll
            for (int i = 0; i < 4; ++i) a[i] = As[kk][ty * 4 + i];
#pragma unroll
            for (int j = 0; j < 4; ++j) b[j] = Ks[kk][tx * 4 + j];
#pragma unroll
            for (int i = 0; i < 4; ++i)
#pragma unroll
                for (int j = 0; j < 4; ++j)
                    acc[i][j] = fmaf(a[i], b[j], acc[i][j]);
        }
        __syncthreads();
    }
    const float scale = 0.08838834764831845f;  // 1/sqrt(128)
#pragma unroll
    for (int i = 0; i < 4; ++i) {
        int sq = bm + ty * 4 + i;
#pragma unroll
        for (int j = 0; j < 4; ++j) {
            int sk = bn + tx * 4 + j;
            out[(size_t)sq * Ss + sk] = (sk <= sq) ? acc[i][j] * scale : MASKVAL;
        }
    }
}

// ---------------------------------------------------------------------------
// Per-row softmax stats: rmax, rinv = 1/sum(exp(a-rmax)). One block per row.
// ---------------------------------------------------------------------------
__global__ __launch_bounds__(256) void rowstats(const float* __restrict__ attn,
                                                float* __restrict__ rmax,
                                                float* __restrict__ rinv)
{
    int row = blockIdx.x;
    const float4* a4 = (const float4*)(attn + (size_t)row * Ss);
    int tid = threadIdx.x;
    float4 x = a4[tid];
    float m = fmaxf(fmaxf(x.x, x.y), fmaxf(x.z, x.w));
#pragma unroll
    for (int off = 32; off; off >>= 1) m = fmaxf(m, __shfl_xor(m, off));
    __shared__ float red[4];
    if ((tid & 63) == 0) red[tid >> 6] = m;
    __syncthreads();
    float mm = fmaxf(fmaxf(red[0], red[1]), fmaxf(red[2], red[3]));
    float s = expf(x.x - mm) + expf(x.y - mm) + expf(x.z - mm) + expf(x.w - mm);
#pragma unroll
    for (int off = 32; off; off >>= 1) s += __shfl_xor(s, off);
    __shared__ float red2[4];
    if ((tid & 63) == 0) red2[tid >> 6] = s;
    __syncthreads();
    if (tid == 0) {
        rmax[row] = mm;
        rinv[row] = 1.0f / (red2[0] + red2[1] + red2[2] + red2[3]);
    }
}

// ---------------------------------------------------------------------------
// A2S sequential scan. One wave (64 lanes) per (b,h). Lane owns 16 keys:
// s = 256*jj + 4*lane + i  (jj,i in 0..3) -> float4-coalesced row loads.
// sel in registers; keep mask written per step as uchar row.
// ---------------------------------------------------------------------------
__global__ __launch_bounds__(64) void scan_kernel(const float* __restrict__ attn,
                                                  const float* __restrict__ rmax,
                                                  const float* __restrict__ rinv,
                                                  unsigned char* __restrict__ keep)
{
    int bh = blockIdx.x;
    int lane = threadIdx.x;
    const float4* A4 = (const float4*)(attn + (size_t)bh * Ss * Ss);
    const float* RM = rmax + (size_t)bh * Ss;
    const float* RI = rinv + (size_t)bh * Ss;
    unsigned char* KP = keep + (size_t)bh * Ss * Ss;
    const float INFv = __int_as_float(0x7f800000);

    float sel[4][4];
#pragma unroll
    for (int jj = 0; jj < 4; ++jj)
#pragma unroll
        for (int i = 0; i < 4; ++i) sel[jj][i] = 0.0f;

    // select0 = sum_{i=0..CB-1} ff^(CB-1-i) * scores[i]  (descending i: w=1,ff,ff^2,..)
    float wgt = 1.0f;
    for (int r = CBc - 1; r >= 0; --r) {
        float rm = RM[r], ri = RI[r];
#pragma unroll
        for (int jj = 0; jj < 4; ++jj) {
            float4 a = A4[(size_t)r * (Ss / 4) + jj * 64 + lane];
            sel[jj][0] += wgt * (expf(a.x - rm) * ri);
            sel[jj][1] += wgt * (expf(a.y - rm) * ri);
            sel[jj][2] += wgt * (expf(a.z - rm) * ri);
            sel[jj][3] += wgt * (expf(a.w - rm) * ri);
        }
        wgt *= FFf;
    }

    unsigned int mbits = 0xFFFFu;

    for (int t = CBc; t <= Ss - 2; ++t) {
        float rm = RM[t], ri = RI[t];
        float cur[4][4];
        float lsum = 0.0f;
#pragma unroll
        for (int jj = 0; jj < 4; ++jj) {
            float4 a = A4[(size_t)t * (Ss / 4) + jj * 64 + lane];
            float s0 = expf(a.x - rm) * ri;
            float s1 = expf(a.y - rm) * ri;
            float s2 = expf(a.z - rm) * ri;
            float s3 = expf(a.w - rm) * ri;
            cur[jj][0] = ((mbits >> (jj * 4 + 0)) & 1) ? s0 : 0.0f;
            cur[jj][1] = ((mbits >> (jj * 4 + 1)) & 1) ? s1 : 0.0f;
            cur[jj][2] = ((mbits >> (jj * 4 + 2)) & 1) ? s2 : 0.0f;
            cur[jj][3] = ((mbits >> (jj * 4 + 3)) & 1) ? s3 : 0.0f;
            lsum += cur[jj][0] + cur[jj][1] + cur[jj][2] + cur[jj][3];
        }
        float tot = lsum;
#pragma unroll
        for (int off = 1; off < 64; off <<= 1) tot += __shfl_xor(tot, off);
        float inv = 1.0f / tot;

        int local = t - RBc;
        float bestv = INFv;
        int besti = 0x7FFFFFFF;
#pragma unroll
        for (int jj = 0; jj < 4; ++jj) {
#pragma unroll
            for (int i = 0; i < 4; ++i) {
                float sv = FFf * sel[jj][i] + cur[jj][i] * inv;
                sel[jj][i] = sv;
                int s = jj * 256 + lane * 4 + i;
                float cand = (s >= SBc && s <= local) ? sv : INFv;
                if (cand < bestv || (cand == bestv && s < besti)) { bestv = cand; besti = s; }
            }
        }
#pragma unroll
        for (int off = 1; off < 64; off <<= 1) {
            float ov = __shfl_xor(bestv, off);
            int   oi = __shfl_xor(besti, off);
            if (ov < bestv || (ov == bestv && oi < besti)) { bestv = ov; besti = oi; }
        }
        // evict besti (first-min). No dynamic register indexing: unrolled compare.
#pragma unroll
        for (int jj = 0; jj < 4; ++jj)
#pragma unroll
            for (int i = 0; i < 4; ++i) {
                int s = jj * 256 + lane * 4 + i;
                if (s == besti) { sel[jj][i] = INFv; mbits &= ~(1u << (jj * 4 + i)); }
            }
        // write keep row t+1
        uchar4* kp4 = (uchar4*)(KP + (size_t)(t + 1) * Ss);
#pragma unroll
        for (int jj = 0; jj < 4; ++jj) {
            uchar4 kb;
            kb.x = (unsigned char)((mbits >> (jj * 4 + 0)) & 1);
            kb.y = (unsigned char)((mbits >> (jj * 4 + 1)) & 1);
            kb.z = (unsigned char)((mbits >> (jj * 4 + 2)) & 1);
            kb.w = (unsigned char)((mbits >> (jj * 4 + 3)) & 1);
            kp4[jj * 64 + lane] = kb;
        }
    }
}

// ---------------------------------------------------------------------------
// Masked softmax, in place (attn -> probs). One block per row.
// ---------------------------------------------------------------------------
__global__ __launch_bounds__(256) void masked_softmax(float* __restrict__ attn,
                                                      const unsigned char* __restrict__ keep)
{
    int row = blockIdx.x;          // bh*S + r
    int r = row % Ss;
    float4* a4 = (float4*)(attn + (size_t)row * Ss);
    int tid = threadIdx.x;
    float4 x = a4[tid];
    if (r > CBc) {
        const uchar4* kp = (const uchar4*)(keep + (size_t)row * Ss);
        uchar4 kb = kp[tid];
        if (!kb.x) x.x = MASKVAL;
        if (!kb.y) x.y = MASKVAL;
        if (!kb.z) x.z = MASKVAL;
        if (!kb.w) x.w = MASKVAL;
    }
    float m = fmaxf(fmaxf(x.x, x.y), fmaxf(x.z, x.w));
#pragma unroll
    for (int off = 32; off; off >>= 1) m = fmaxf(m, __shfl_xor(m, off));
    __shared__ float red[4];
    if ((tid & 63) == 0) red[tid >> 6] = m;
    __syncthreads();
    float mm = fmaxf(fmaxf(red[0], red[1]), fmaxf(red[2], red[3]));
    float e0 = expf(x.x - mm), e1 = expf(x.y - mm);
    float e2 = expf(x.z - mm), e3 = expf(x.w - mm);
    float s = e0 + e1 + e2 + e3;
#pragma unroll
    for (int off = 32; off; off >>= 1) s += __shfl_xor(s, off);
    __shared__ float red2[4];
    if ((tid & 63) == 0) red2[tid >> 6] = s;
    __syncthreads();
    float inv = 1.0f / (red2[0] + red2[1] + red2[2] + red2[3]);
    a4[tid] = make_float4(e0 * inv, e1 * inv, e2 * inv, e3 * inv);
}

// ---------------------------------------------------------------------------
// ctx = probs @ v, per (b,h). Output layout [b, s, h*HD+d] for the wo GEMM.
// K-loop causally truncated (probs[sq][k]=0 for k>sq).
// ---------------------------------------------------------------------------
__global__ __launch_bounds__(256) void pv_gemm(const float* __restrict__ probs,
                                               const float* __restrict__ v,
                                               float* __restrict__ ctx)
{
    int bh = blockIdx.z;
    int b_ = bh / NHh, h_ = bh % NHh;
    const float* P = probs + (size_t)bh * Ss * Ss;
    const float* V = v     + (size_t)bh * Ss * HDd;
    int bm = blockIdx.y * 64, bn = blockIdx.x * 64;
    int tid = threadIdx.x, tx = tid & 15, ty = tid >> 4;
    __shared__ float As[16][65];
    __shared__ float Bs[16][64];
    float acc[4][4] = {};
    int kend = bm + 64;  // causal: rows in this tile have no mass beyond bm+63
    for (int k0 = 0; k0 < kend; k0 += 16) {
#pragma unroll
        for (int l = 0; l < 4; ++l) {
            int idx = tid + l * 256;
            int r = idx >> 4, c = idx & 15;
            As[c][r] = P[(size_t)(bm + r) * Ss + k0 + c];
        }
#pragma unroll
        for (int l = 0; l < 4; ++l) {
            int idx = tid + l * 256;
            int r = idx >> 6, c = idx & 63;
            Bs[r][c] = V[(size_t)(k0 + r) * HDd + bn + c];
        }
        __syncthreads();
#pragma unroll
        for (int kk = 0; kk < 16; ++kk) {
            float a[4], b[4];
#pragma unroll
            for (int i = 0; i < 4; ++i) a[i] = As[kk][ty * 4 + i];
#pragma unroll
            for (int j = 0; j < 4; ++j) b[j] = Bs[kk][tx * 4 + j];
#pragma unroll
            for (int i = 0; i < 4; ++i)
#pragma unroll
                for (int j = 0; j < 4; ++j)
                    acc[i][j] = fmaf(a[i], b[j], acc[i][j]);
        }
        __syncthreads();
    }
#pragma unroll
    for (int i = 0; i < 4; ++i) {
        int sq = bm + ty * 4 + i;
#pragma unroll
        for (int j = 0; j < 4; ++j) {
            int d = bn + tx * 4 + j;
            ctx[(size_t)(b_ * Ss + sq) * HIDd + h_ * HDd + d] = acc[i][j];
        }
    }
}

// ---------------------------------------------------------------------------
extern "C" void kernel_launch(void* const* d_in, const int* in_sizes, int n_in,
                              void* d_out, int out_size, void* d_ws, size_t ws_size,
                              hipStream_t stream)
{
    const float* hs = (const float*)d_in[0];
    const float* wq = (const float*)d_in[1];
    const float* wk = (const float*)d_in[2];
    const float* wv = (const float*)d_in[3];
    const float* wo = (const float*)d_in[4];
    float* out = (float*)d_out;

    float* ws = (float*)d_ws;
    size_t off = 0;
    float* q    = ws + off; off += (size_t)NBH * Ss * HDd;   // 4 M floats
    float* k    = ws + off; off += (size_t)NBH * Ss * HDd;
    float* v    = ws + off; off += (size_t)NBH * Ss * HDd;
    float* attn = ws + off; off += (size_t)NBH * Ss * Ss;    // 32 M floats (reused as probs)
    float* ctx  = ws + off; off += (size_t)NBH * Ss * HDd;
    float* rmx  = ws + off; off += NROWS;
    float* rin  = ws + off; off += NROWS;
    unsigned char* keep = (unsigned char*)(ws + off);        // 32 MB u8

    dim3 blk(256);
    dim3 g1(HIDd / 64, (Bb * Ss) / 64);   // 32 x 32

    gemm64x64<1><<<g1, blk, 0, stream>>>(hs, wq, q, Bb * Ss, HIDd, HIDd);
    gemm64x64<1><<<g1, blk, 0, stream>>>(hs, wk, k, Bb * Ss, HIDd, HIDd);
    gemm64x64<1><<<g1, blk, 0, stream>>>(hs, wv, v, Bb * Ss, HIDd, HIDd);

    rope_qk<<<dim3(NBH * Ss), dim3(64), 0, stream>>>(q, k);

    attn_qk<<<dim3(Ss / 64, Ss / 64, NBH), blk, 0, stream>>>(q, k, attn);

    rowstats<<<dim3(NROWS), blk, 0, stream>>>(attn, rmx, rin);

    scan_kernel<<<dim3(NBH), dim3(64), 0, stream>>>(attn, rmx, rin, keep);

    masked_softmax<<<dim3(NROWS), blk, 0, stream>>>(attn, keep);

    pv_gemm<<<dim3(HDd / 64, Ss / 64, NBH), blk, 0, stream>>>(attn, v, ctx);

    gemm64x64<0><<<g1, blk, 0, stream>>>(ctx, wo, out, Bb * Ss, HIDd, HIDd);
}

// Round 2
// 2655.183 us; speedup vs baseline: 1.6067x; 1.6067x over previous
//
#include <hip/hip_runtime.h>
#include <math.h>

// Problem constants (from reference)
#define Bb    2
#define Ss    1024
#define HIDd  2048
#define NHh   16
#define HDd   128
#define SBc   20      // floor(0.02*1024+0.5)
#define SELBc 61      // floor(0.06*1024+0.5)
#define RBc   82      // floor(0.08*1024+0.5)
#define CBc   163     // SB+SELB+RB
#define FFf   0.9f
#define MASKVAL (-3.4028234663852886e38f)
#define NBH   (Bb*NHh)       // 32
#define NROWS (NBH*Ss)       // 32768

// ---------------------------------------------------------------------------
// Generic 64x64-tile fp32 GEMM, 256 threads, 4x4 micro-tile.
// MODE 0: C[m*N+n] plain row-major.
// MODE 1: qkv permute: m=b*S+s, n=h*HD+d  ->  C[((b*NH+h)*S+s)*HD+d]
// ---------------------------------------------------------------------------
template<int MODE>
__global__ __launch_bounds__(256) void gemm64x64(const float* __restrict__ A,
                                                 const float* __restrict__ Bm,
                                                 float* __restrict__ C,
                                                 int M, int N, int K)
{
    __shared__ float As[16][65];   // [k][m], padded
    __shared__ float Bs[16][64];   // [k][n]
    int tid = threadIdx.x;
    int tx = tid & 15, ty = tid >> 4;
    int bm = blockIdx.y * 64, bn = blockIdx.x * 64;
    float acc[4][4] = {};
    for (int k0 = 0; k0 < K; k0 += 16) {
#pragma unroll
        for (int l = 0; l < 4; ++l) {
            int idx = tid + l * 256;
            int r = idx >> 4, c = idx & 15;
            As[c][r] = A[(size_t)(bm + r) * K + k0 + c];
        }
#pragma unroll
        for (int l = 0; l < 4; ++l) {
            int idx = tid + l * 256;
            int r = idx >> 6, c = idx & 63;
            Bs[r][c] = Bm[(size_t)(k0 + r) * N + bn + c];
        }
        __syncthreads();
#pragma unroll
        for (int kk = 0; kk < 16; ++kk) {
            float a[4], b[4];
#pragma unroll
            for (int i = 0; i < 4; ++i) a[i] = As[kk][ty * 4 + i];
#pragma unroll
            for (int j = 0; j < 4; ++j) b[j] = Bs[kk][tx * 4 + j];
#pragma unroll
            for (int i = 0; i < 4; ++i)
#pragma unroll
                for (int j = 0; j < 4; ++j)
                    acc[i][j] = fmaf(a[i], b[j], acc[i][j]);
        }
        __syncthreads();
    }
#pragma unroll
    for (int i = 0; i < 4; ++i) {
        int m = bm + ty * 4 + i;
#pragma unroll
        for (int j = 0; j < 4; ++j) {
            int n = bn + tx * 4 + j;
            if (MODE == 0) {
                C[(size_t)m * N + n] = acc[i][j];
            } else {
                int b_ = m / Ss, s_ = m % Ss;
                int h_ = n / HDd, d_ = n % HDd;
                C[(size_t)((b_ * NHh + h_) * Ss + s_) * HDd + d_] = acc[i][j];
            }
        }
    }
}

// ---------------------------------------------------------------------------
// RoPE, in-place on q and k. One block per (b,h,s), 64 threads (pair d, d+64).
// ---------------------------------------------------------------------------
__global__ __launch_bounds__(64) void rope_qk(float* __restrict__ q, float* __restrict__ k)
{
    int idx = blockIdx.x;          // bh*S + s
    int s = idx % Ss;
    int d = threadIdx.x;           // 0..63
    float inv = powf(10000.0f, -2.0f * (float)d / 128.0f);
    float fr = (float)s * inv;
    float c = cosf(fr), sn = sinf(fr);
    size_t base = (size_t)idx * HDd;
    float q1 = q[base + d], q2 = q[base + d + 64];
    q[base + d]      = q1 * c - q2 * sn;
    q[base + d + 64] = q2 * c + q1 * sn;
    float k1 = k[base + d], k2 = k[base + d + 64];
    k[base + d]      = k1 * c - k2 * sn;
    k[base + d + 64] = k2 * c + k1 * sn;
}

// ---------------------------------------------------------------------------
// attn = q k^T / sqrt(HD), causal-masked to MASKVAL. 64x64 tiles per (b,h).
// ---------------------------------------------------------------------------
__global__ __launch_bounds__(256) void attn_qk(const float* __restrict__ q,
                                               const float* __restrict__ kmat,
                                               float* __restrict__ attn)
{
    int bh = blockIdx.z;
    int bm = blockIdx.y * 64, bn = blockIdx.x * 64;
    float* out = attn + (size_t)bh * Ss * Ss;
    int tid = threadIdx.x, tx = tid & 15, ty = tid >> 4;

    if (blockIdx.x > blockIdx.y) {  // entire tile above diagonal -> masked
#pragma unroll
        for (int i = 0; i < 4; ++i) {
            int sq = bm + ty * 4 + i;
#pragma unroll
            for (int j = 0; j < 4; ++j) {
                int sk = bn + tx * 4 + j;
                out[(size_t)sq * Ss + sk] = MASKVAL;
            }
        }
        return;
    }
    const float* Q  = q    + (size_t)bh * Ss * HDd;
    const float* Kh = kmat + (size_t)bh * Ss * HDd;
    __shared__ float As[16][65], Ks[16][65];
    float acc[4][4] = {};
    for (int k0 = 0; k0 < HDd; k0 += 16) {
#pragma unroll
        for (int l = 0; l < 4; ++l) {
            int idx = tid + l * 256;
            int r = idx >> 4, c = idx & 15;
            As[c][r] = Q[(size_t)(bm + r) * HDd + k0 + c];
            Ks[c][r] = Kh[(size_t)(bn + r) * HDd + k0 + c];
        }
        __syncthreads();
#pragma unroll
        for (int kk = 0; kk < 16; ++kk) {
            float a[4], b[4];
#pragma unroll
            for (int i = 0; i < 4; ++i) a[i] = As[kk][ty * 4 + i];
#pragma unroll
            for (int j = 0; j < 4; ++j) b[j] = Ks[kk][tx * 4 + j];
#pragma unroll
            for (int i = 0; i < 4; ++i)
#pragma unroll
                for (int j = 0; j < 4; ++j)
                    acc[i][j] = fmaf(a[i], b[j], acc[i][j]);
        }
        __syncthreads();
    }
    const float scale = 0.08838834764831845f;  // 1/sqrt(128)
#pragma unroll
    for (int i = 0; i < 4; ++i) {
        int sq = bm + ty * 4 + i;
#pragma unroll
        for (int j = 0; j < 4; ++j) {
            int sk = bn + tx * 4 + j;
            out[(size_t)sq * Ss + sk] = (sk <= sq) ? acc[i][j] * scale : MASKVAL;
        }
    }
}

// ---------------------------------------------------------------------------
// Row softmax IN PLACE: attn -> scores = exp(a - rowmax) / rowsum.
// One block (256 threads = 4 waves) per row, float4 per thread.
// Masked entries (MASKVAL) become exactly 0.
// ---------------------------------------------------------------------------
__global__ __launch_bounds__(256) void softmax_rows(float* __restrict__ attn)
{
    int row = blockIdx.x;
    float4* a4 = (float4*)(attn + (size_t)row * Ss);
    int tid = threadIdx.x;
    float4 x = a4[tid];
    float m = fmaxf(fmaxf(x.x, x.y), fmaxf(x.z, x.w));
#pragma unroll
    for (int off = 32; off; off >>= 1) m = fmaxf(m, __shfl_xor(m, off));
    __shared__ float red[4];
    if ((tid & 63) == 0) red[tid >> 6] = m;
    __syncthreads();
    float mm = fmaxf(fmaxf(red[0], red[1]), fmaxf(red[2], red[3]));
    float e0 = expf(x.x - mm), e1 = expf(x.y - mm);
    float e2 = expf(x.z - mm), e3 = expf(x.w - mm);
    float s = e0 + e1 + e2 + e3;
#pragma unroll
    for (int off = 32; off; off >>= 1) s += __shfl_xor(s, off);
    __shared__ float red2[4];
    if ((tid & 63) == 0) red2[tid >> 6] = s;
    __syncthreads();
    float inv = 1.0f / (red2[0] + red2[1] + red2[2] + red2[3]);
    a4[tid] = make_float4(e0 * inv, e1 * inv, e2 * inv, e3 * inv);
}

// ---------------------------------------------------------------------------
// A2S sequential scan over precomputed scores. One wave per (b,h).
// Lane owns 16 keys: s = 256*jj + 4*lane + i -> float4-coalesced row loads.
// Chain optimizations vs round 1: no exp (scores precomputed), 2-deep row
// prefetch into registers, argmin packed into u64 (valbits<<32 | idx) so the
// cross-lane argmin is a single u64 min butterfly with first-min tie-break.
// ---------------------------------------------------------------------------
__global__ __launch_bounds__(64) void scan_kernel2(const float* __restrict__ scores,
                                                   unsigned char* __restrict__ keep)
{
    int bh = blockIdx.x;
    int lane = threadIdx.x;
    const float4* A4 = (const float4*)(scores + (size_t)bh * Ss * Ss);
    unsigned char* KP = keep + (size_t)bh * Ss * Ss;
    const float INFv = __int_as_float(0x7f800000);

    float sel[4][4] = {};

    // ---- warmup: select0 = sum_{r=0..CB-1} ff^(CB-1-r) * scores[r]
    // iterate r descending so wgt starts at 1 (exact), with 1-deep prefetch
    {
        float4 nxt[4];
#pragma unroll
        for (int jj = 0; jj < 4; ++jj) nxt[jj] = A4[(size_t)(CBc - 1) * 256 + jj * 64 + lane];
        float wgt = 1.0f;
        for (int r = CBc - 1; r >= 0; --r) {
            float4 a[4];
#pragma unroll
            for (int jj = 0; jj < 4; ++jj) a[jj] = nxt[jj];
            int rp = (r > 0) ? r - 1 : 0;
#pragma unroll
            for (int jj = 0; jj < 4; ++jj) nxt[jj] = A4[(size_t)rp * 256 + jj * 64 + lane];
#pragma unroll
            for (int jj = 0; jj < 4; ++jj) {
                sel[jj][0] = fmaf(wgt, a[jj].x, sel[jj][0]);
                sel[jj][1] = fmaf(wgt, a[jj].y, sel[jj][1]);
                sel[jj][2] = fmaf(wgt, a[jj].z, sel[jj][2]);
                sel[jj][3] = fmaf(wgt, a[jj].w, sel[jj][3]);
            }
            wgt *= FFf;
        }
    }

    unsigned int mbits = 0xFFFFu;

    // ---- main scan, 2-deep prefetch pipeline
    float4 buf0[4], buf1[4];
#pragma unroll
    for (int jj = 0; jj < 4; ++jj) buf0[jj] = A4[(size_t)CBc * 256 + jj * 64 + lane];
#pragma unroll
    for (int jj = 0; jj < 4; ++jj) buf1[jj] = A4[(size_t)(CBc + 1) * 256 + jj * 64 + lane];

    for (int t = CBc; t <= Ss - 2; ++t) {
        float4 a[4];
#pragma unroll
        for (int jj = 0; jj < 4; ++jj) a[jj] = buf0[jj];
#pragma unroll
        for (int jj = 0; jj < 4; ++jj) buf0[jj] = buf1[jj];
        int tp = (t + 2 <= Ss - 1) ? t + 2 : Ss - 1;
#pragma unroll
        for (int jj = 0; jj < 4; ++jj) buf1[jj] = A4[(size_t)tp * 256 + jj * 64 + lane];

        // cur = scores * mask; local sum
        float cur[4][4];
        float lsum = 0.0f;
#pragma unroll
        for (int jj = 0; jj < 4; ++jj) {
            cur[jj][0] = ((mbits >> (jj * 4 + 0)) & 1) ? a[jj].x : 0.0f;
            cur[jj][1] = ((mbits >> (jj * 4 + 1)) & 1) ? a[jj].y : 0.0f;
            cur[jj][2] = ((mbits >> (jj * 4 + 2)) & 1) ? a[jj].z : 0.0f;
            cur[jj][3] = ((mbits >> (jj * 4 + 3)) & 1) ? a[jj].w : 0.0f;
            lsum += (cur[jj][0] + cur[jj][1]) + (cur[jj][2] + cur[jj][3]);
        }
        float tot = lsum;
#pragma unroll
        for (int off = 1; off < 64; off <<= 1) tot += __shfl_xor(tot, off);
        float inv = 1.0f / tot;

        // sel update + windowed first-argmin packed as u64
        int local = t - RBc;
        unsigned long long best = 0xFFFFFFFFFFFFFFFFull;
#pragma unroll
        for (int jj = 0; jj < 4; ++jj) {
#pragma unroll
            for (int i = 0; i < 4; ++i) {
                float sv = fmaf(FFf, sel[jj][i], cur[jj][i] * inv);
                sel[jj][i] = sv;
                int s = jj * 256 + lane * 4 + i;
                float cand = (s >= SBc && s <= local) ? sv : INFv;
                unsigned long long key =
                    ((unsigned long long)__float_as_uint(cand) << 32) | (unsigned)s;
                best = (key < best) ? key : best;
            }
        }
#pragma unroll
        for (int off = 1; off < 64; off <<= 1) {
            unsigned long long o = __shfl_xor(best, off);
            best = (o < best) ? o : best;
        }
        int besti = (int)(best & 0xFFFFFFFFu);

        // evict (no dynamic register indexing: unrolled compare)
#pragma unroll
        for (int jj = 0; jj < 4; ++jj)
#pragma unroll
            for (int i = 0; i < 4; ++i) {
                int s = jj * 256 + lane * 4 + i;
                if (s == besti) { sel[jj][i] = INFv; mbits &= ~(1u << (jj * 4 + i)); }
            }

        // write keep row t+1
        uchar4* kp4 = (uchar4*)(KP + (size_t)(t + 1) * Ss);
#pragma unroll
        for (int jj = 0; jj < 4; ++jj) {
            uchar4 kb;
            kb.x = (unsigned char)((mbits >> (jj * 4 + 0)) & 1);
            kb.y = (unsigned char)((mbits >> (jj * 4 + 1)) & 1);
            kb.z = (unsigned char)((mbits >> (jj * 4 + 2)) & 1);
            kb.w = (unsigned char)((mbits >> (jj * 4 + 3)) & 1);
            kp4[jj * 64 + lane] = kb;
        }
    }
}

// ---------------------------------------------------------------------------
// Masked renormalization IN PLACE: probs = scores*keep / sum(scores*keep).
// Identical to re-softmaxing the masked logits (same exp terms, same ratio).
// One block per row.
// ---------------------------------------------------------------------------
__global__ __launch_bounds__(256) void renorm_rows(float* __restrict__ scores,
                                                   const unsigned char* __restrict__ keep)
{
    int row = blockIdx.x;          // bh*S + r
    int r = row % Ss;
    float4* a4 = (float4*)(scores + (size_t)row * Ss);
    int tid = threadIdx.x;
    float4 x = a4[tid];
    if (r > CBc) {
        const uchar4* kp = (const uchar4*)(keep + (size_t)row * Ss);
        uchar4 kb = kp[tid];
        if (!kb.x) x.x = 0.0f;
        if (!kb.y) x.y = 0.0f;
        if (!kb.z) x.z = 0.0f;
        if (!kb.w) x.w = 0.0f;
    }
    float s = (x.x + x.y) + (x.z + x.w);
#pragma unroll
    for (int off = 32; off; off >>= 1) s += __shfl_xor(s, off);
    __shared__ float red2[4];
    if ((tid & 63) == 0) red2[tid >> 6] = s;
    __syncthreads();
    float inv = 1.0f / (red2[0] + red2[1] + red2[2] + red2[3]);
    a4[tid] = make_float4(x.x * inv, x.y * inv, x.z * inv, x.w * inv);
}

// ---------------------------------------------------------------------------
// ctx = probs @ v, per (b,h). Output layout [b, s, h*HD+d] for the wo GEMM.
// K-loop causally truncated (probs[sq][k]=0 for k>sq).
// ---------------------------------------------------------------------------
__global__ __launch_bounds__(256) void pv_gemm(const float* __restrict__ probs,
                                               const float* __restrict__ v,
                                               float* __restrict__ ctx)
{
    int bh = blockIdx.z;
    int b_ = bh / NHh, h_ = bh % NHh;
    const float* P = probs + (size_t)bh * Ss * Ss;
    const float* V = v     + (size_t)bh * Ss * HDd;
    int bm = blockIdx.y * 64, bn = blockIdx.x * 64;
    int tid = threadIdx.x, tx = tid & 15, ty = tid >> 4;
    __shared__ float As[16][65];
    __shared__ float Bs[16][64];
    float acc[4][4] = {};
    int kend = bm + 64;  // causal: rows in this tile have no mass beyond bm+63
    for (int k0 = 0; k0 < kend; k0 += 16) {
#pragma unroll
        for (int l = 0; l < 4; ++l) {
            int idx = tid + l * 256;
            int r = idx >> 4, c = idx & 15;
            As[c][r] = P[(size_t)(bm + r) * Ss + k0 + c];
        }
#pragma unroll
        for (int l = 0; l < 4; ++l) {
            int idx = tid + l * 256;
            int r = idx >> 6, c = idx & 63;
            Bs[r][c] = V[(size_t)(k0 + r) * HDd + bn + c];
        }
        __syncthreads();
#pragma unroll
        for (int kk = 0; kk < 16; ++kk) {
            float a[4], b[4];
#pragma unroll
            for (int i = 0; i < 4; ++i) a[i] = As[kk][ty * 4 + i];
#pragma unroll
            for (int j = 0; j < 4; ++j) b[j] = Bs[kk][tx * 4 + j];
#pragma unroll
            for (int i = 0; i < 4; ++i)
#pragma unroll
                for (int j = 0; j < 4; ++j)
                    acc[i][j] = fmaf(a[i], b[j], acc[i][j]);
        }
        __syncthreads();
    }
#pragma unroll
    for (int i = 0; i < 4; ++i) {
        int sq = bm + ty * 4 + i;
#pragma unroll
        for (int j = 0; j < 4; ++j) {
            int d = bn + tx * 4 + j;
            ctx[(size_t)(b_ * Ss + sq) * HIDd + h_ * HDd + d] = acc[i][j];
        }
    }
}

// ---------------------------------------------------------------------------
extern "C" void kernel_launch(void* const* d_in, const int* in_sizes, int n_in,
                              void* d_out, int out_size, void* d_ws, size_t ws_size,
                              hipStream_t stream)
{
    const float* hs = (const float*)d_in[0];
    const float* wq = (const float*)d_in[1];
    const float* wk = (const float*)d_in[2];
    const float* wv = (const float*)d_in[3];
    const float* wo = (const float*)d_in[4];
    float* out = (float*)d_out;

    float* ws = (float*)d_ws;
    size_t off = 0;
    float* q    = ws + off; off += (size_t)NBH * Ss * HDd;   // 4 M floats
    float* k    = ws + off; off += (size_t)NBH * Ss * HDd;
    float* v    = ws + off; off += (size_t)NBH * Ss * HDd;
    float* attn = ws + off; off += (size_t)NBH * Ss * Ss;    // 32 M floats (attn -> scores -> probs)
    float* ctx  = ws + off; off += (size_t)NBH * Ss * HDd;
    unsigned char* keep = (unsigned char*)(ws + off);        // 32 MB u8

    dim3 blk(256);
    dim3 g1(HIDd / 64, (Bb * Ss) / 64);   // 32 x 32

    gemm64x64<1><<<g1, blk, 0, stream>>>(hs, wq, q, Bb * Ss, HIDd, HIDd);
    gemm64x64<1><<<g1, blk, 0, stream>>>(hs, wk, k, Bb * Ss, HIDd, HIDd);
    gemm64x64<1><<<g1, blk, 0, stream>>>(hs, wv, v, Bb * Ss, HIDd, HIDd);

    rope_qk<<<dim3(NBH * Ss), dim3(64), 0, stream>>>(q, k);

    attn_qk<<<dim3(Ss / 64, Ss / 64, NBH), blk, 0, stream>>>(q, k, attn);

    // attn -> scores (normalized softmax probs, causal zeros), in place
    softmax_rows<<<dim3(NROWS), blk, 0, stream>>>(attn);

    scan_kernel2<<<dim3(NBH), dim3(64), 0, stream>>>(attn, keep);

    // scores -> final probs (keep-mask + renormalize), in place
    renorm_rows<<<dim3(NROWS), blk, 0, stream>>>(attn, keep);

    pv_gemm<<<dim3(HDd / 64, Ss / 64, NBH), blk, 0, stream>>>(attn, v, ctx);

    gemm64x64<0><<<g1, blk, 0, stream>>>(ctx, wo, out, Bb * Ss, HIDd, HIDd);
}

// Round 3
// 2522.690 us; speedup vs baseline: 1.6911x; 1.0525x over previous
//
#include <hip/hip_runtime.h>
#include <math.h>

// Problem constants (from reference)
#define Bb    2
#define Ss    1024
#define HIDd  2048
#define NHh   16
#define HDd   128
#define SBc   20      // floor(0.02*1024+0.5)
#define SELBc 61      // floor(0.06*1024+0.5)
#define RBc   82      // floor(0.08*1024+0.5)
#define CBc   163     // SB+SELB+RB
#define FFf   0.9f
#define MASKVAL (-3.4028234663852886e38f)
#define NBH   (Bb*NHh)       // 32
#define NROWS (NBH*Ss)       // 32768

// ---------------------------------------------------------------------------
// Generic 64x64-tile fp32 GEMM, 256 threads, 4x4 micro-tile.
// MODE 0: C[m*N+n] plain row-major.
// MODE 1: qkv permute: m=b*S+s, n=h*HD+d  ->  C[((b*NH+h)*S+s)*HD+d]
// ---------------------------------------------------------------------------
template<int MODE>
__global__ __launch_bounds__(256) void gemm64x64(const float* __restrict__ A,
                                                 const float* __restrict__ Bm,
                                                 float* __restrict__ C,
                                                 int M, int N, int K)
{
    __shared__ float As[16][65];   // [k][m], padded
    __shared__ float Bs[16][64];   // [k][n]
    int tid = threadIdx.x;
    int tx = tid & 15, ty = tid >> 4;
    int bm = blockIdx.y * 64, bn = blockIdx.x * 64;
    float acc[4][4] = {};
    for (int k0 = 0; k0 < K; k0 += 16) {
#pragma unroll
        for (int l = 0; l < 4; ++l) {
            int idx = tid + l * 256;
            int r = idx >> 4, c = idx & 15;
            As[c][r] = A[(size_t)(bm + r) * K + k0 + c];
        }
#pragma unroll
        for (int l = 0; l < 4; ++l) {
            int idx = tid + l * 256;
            int r = idx >> 6, c = idx & 63;
            Bs[r][c] = Bm[(size_t)(k0 + r) * N + bn + c];
        }
        __syncthreads();
#pragma unroll
        for (int kk = 0; kk < 16; ++kk) {
            float a[4], b[4];
#pragma unroll
            for (int i = 0; i < 4; ++i) a[i] = As[kk][ty * 4 + i];
#pragma unroll
            for (int j = 0; j < 4; ++j) b[j] = Bs[kk][tx * 4 + j];
#pragma unroll
            for (int i = 0; i < 4; ++i)
#pragma unroll
                for (int j = 0; j < 4; ++j)
                    acc[i][j] = fmaf(a[i], b[j], acc[i][j]);
        }
        __syncthreads();
    }
#pragma unroll
    for (int i = 0; i < 4; ++i) {
        int m = bm + ty * 4 + i;
#pragma unroll
        for (int j = 0; j < 4; ++j) {
            int n = bn + tx * 4 + j;
            if (MODE == 0) {
                C[(size_t)m * N + n] = acc[i][j];
            } else {
                int b_ = m / Ss, s_ = m % Ss;
                int h_ = n / HDd, d_ = n % HDd;
                C[(size_t)((b_ * NHh + h_) * Ss + s_) * HDd + d_] = acc[i][j];
            }
        }
    }
}

// ---------------------------------------------------------------------------
// RoPE, in-place on q and k. One block per (b,h,s), 64 threads (pair d, d+64).
// ---------------------------------------------------------------------------
__global__ __launch_bounds__(64) void rope_qk(float* __restrict__ q, float* __restrict__ k)
{
    int idx = blockIdx.x;          // bh*S + s
    int s = idx % Ss;
    int d = threadIdx.x;           // 0..63
    float inv = powf(10000.0f, -2.0f * (float)d / 128.0f);
    float fr = (float)s * inv;
    float c = cosf(fr), sn = sinf(fr);
    size_t base = (size_t)idx * HDd;
    float q1 = q[base + d], q2 = q[base + d + 64];
    q[base + d]      = q1 * c - q2 * sn;
    q[base + d + 64] = q2 * c + q1 * sn;
    float k1 = k[base + d], k2 = k[base + d + 64];
    k[base + d]      = k1 * c - k2 * sn;
    k[base + d + 64] = k2 * c + k1 * sn;
}

// ---------------------------------------------------------------------------
// attn = q k^T / sqrt(HD), causal-masked to MASKVAL. 64x64 tiles per (b,h).
// ---------------------------------------------------------------------------
__global__ __launch_bounds__(256) void attn_qk(const float* __restrict__ q,
                                               const float* __restrict__ kmat,
                                               float* __restrict__ attn)
{
    int bh = blockIdx.z;
    int bm = blockIdx.y * 64, bn = blockIdx.x * 64;
    float* out = attn + (size_t)bh * Ss * Ss;
    int tid = threadIdx.x, tx = tid & 15, ty = tid >> 4;

    if (blockIdx.x > blockIdx.y) {  // entire tile above diagonal -> masked
#pragma unroll
        for (int i = 0; i < 4; ++i) {
            int sq = bm + ty * 4 + i;
#pragma unroll
            for (int j = 0; j < 4; ++j) {
                int sk = bn + tx * 4 + j;
                out[(size_t)sq * Ss + sk] = MASKVAL;
            }
        }
        return;
    }
    const float* Q  = q    + (size_t)bh * Ss * HDd;
    const float* Kh = kmat + (size_t)bh * Ss * HDd;
    __shared__ float As[16][65], Ks[16][65];
    float acc[4][4] = {};
    for (int k0 = 0; k0 < HDd; k0 += 16) {
#pragma unroll
        for (int l = 0; l < 4; ++l) {
            int idx = tid + l * 256;
            int r = idx >> 4, c = idx & 15;
            As[c][r] = Q[(size_t)(bm + r) * HDd + k0 + c];
            Ks[c][r] = Kh[(size_t)(bn + r) * HDd + k0 + c];
        }
        __syncthreads();
#pragma unroll
        for (int kk = 0; kk < 16; ++kk) {
            float a[4], b[4];
#pragma unroll
            for (int i = 0; i < 4; ++i) a[i] = As[kk][ty * 4 + i];
#pragma unroll
            for (int j = 0; j < 4; ++j) b[j] = Ks[kk][tx * 4 + j];
#pragma unroll
            for (int i = 0; i < 4; ++i)
#pragma unroll
                for (int j = 0; j < 4; ++j)
                    acc[i][j] = fmaf(a[i], b[j], acc[i][j]);
        }
        __syncthreads();
    }
    const float scale = 0.08838834764831845f;  // 1/sqrt(128)
#pragma unroll
    for (int i = 0; i < 4; ++i) {
        int sq = bm + ty * 4 + i;
#pragma unroll
        for (int j = 0; j < 4; ++j) {
            int sk = bn + tx * 4 + j;
            out[(size_t)sq * Ss + sk] = (sk <= sq) ? acc[i][j] * scale : MASKVAL;
        }
    }
}

// ---------------------------------------------------------------------------
// Row softmax IN PLACE: attn -> scores = exp(a - rowmax) / rowsum.
// One block (256 threads = 4 waves) per row, float4 per thread.
// Masked entries (MASKVAL) become exactly 0.
// ---------------------------------------------------------------------------
__global__ __launch_bounds__(256) void softmax_rows(float* __restrict__ attn)
{
    int row = blockIdx.x;
    float4* a4 = (float4*)(attn + (size_t)row * Ss);
    int tid = threadIdx.x;
    float4 x = a4[tid];
    float m = fmaxf(fmaxf(x.x, x.y), fmaxf(x.z, x.w));
#pragma unroll
    for (int off = 32; off; off >>= 1) m = fmaxf(m, __shfl_xor(m, off));
    __shared__ float red[4];
    if ((tid & 63) == 0) red[tid >> 6] = m;
    __syncthreads();
    float mm = fmaxf(fmaxf(red[0], red[1]), fmaxf(red[2], red[3]));
    float e0 = expf(x.x - mm), e1 = expf(x.y - mm);
    float e2 = expf(x.z - mm), e3 = expf(x.w - mm);
    float s = e0 + e1 + e2 + e3;
#pragma unroll
    for (int off = 32; off; off >>= 1) s += __shfl_xor(s, off);
    __shared__ float red2[4];
    if ((tid & 63) == 0) red2[tid >> 6] = s;
    __syncthreads();
    float inv = 1.0f / (red2[0] + red2[1] + red2[2] + red2[3]);
    a4[tid] = make_float4(e0 * inv, e1 * inv, e2 * inv, e3 * inv);
}

// ---------------------------------------------------------------------------
// DPP cross-lane helpers (VALU-latency, no LDS pipe).
// row16_*: butterfly within each row of 16 lanes (quad_perm xor1, xor2,
// half_mirror, mirror) -> every lane holds its row-of-16 reduction.
// wave_*: + 4x readlane (lanes 0/16/32/48) combined with the SAME
// association as the old xor16/xor32 butterfly -> bit-exact totals.
// ---------------------------------------------------------------------------
template<int CTRL>
__device__ __forceinline__ int dpp_i(int x) {
    return __builtin_amdgcn_update_dpp(0, x, CTRL, 0xF, 0xF, true);
}
__device__ __forceinline__ float wave_sum64(float x) {
    x += __int_as_float(dpp_i<0xB1>(__float_as_int(x)));   // quad_perm [1,0,3,2]  (xor1)
    x += __int_as_float(dpp_i<0x4E>(__float_as_int(x)));   // quad_perm [2,3,0,1]  (xor2)
    x += __int_as_float(dpp_i<0x141>(__float_as_int(x)));  // row_half_mirror      (xor4 equiv)
    x += __int_as_float(dpp_i<0x140>(__float_as_int(x)));  // row_mirror           (xor8 equiv)
    int xi = __float_as_int(x);
    float a = __int_as_float(__builtin_amdgcn_readlane(xi, 0));
    float b = __int_as_float(__builtin_amdgcn_readlane(xi, 16));
    float c = __int_as_float(__builtin_amdgcn_readlane(xi, 32));
    float d = __int_as_float(__builtin_amdgcn_readlane(xi, 48));
    return (a + c) + (b + d);  // matches xor16 then xor32 association: (l0+l32)+(l16+l48)
}
__device__ __forceinline__ float wave_min64f(float x) {
    x = fminf(x, __int_as_float(dpp_i<0xB1>(__float_as_int(x))));
    x = fminf(x, __int_as_float(dpp_i<0x4E>(__float_as_int(x))));
    x = fminf(x, __int_as_float(dpp_i<0x141>(__float_as_int(x))));
    x = fminf(x, __int_as_float(dpp_i<0x140>(__float_as_int(x))));
    int xi = __float_as_int(x);
    float a = __int_as_float(__builtin_amdgcn_readlane(xi, 0));
    float b = __int_as_float(__builtin_amdgcn_readlane(xi, 16));
    float c = __int_as_float(__builtin_amdgcn_readlane(xi, 32));
    float d = __int_as_float(__builtin_amdgcn_readlane(xi, 48));
    return fminf(fminf(a, b), fminf(c, d));
}
__device__ __forceinline__ unsigned wave_min64u(unsigned x) {
    unsigned o;
    o = (unsigned)dpp_i<0xB1>((int)x);  x = (o < x) ? o : x;
    o = (unsigned)dpp_i<0x4E>((int)x);  x = (o < x) ? o : x;
    o = (unsigned)dpp_i<0x141>((int)x); x = (o < x) ? o : x;
    o = (unsigned)dpp_i<0x140>((int)x); x = (o < x) ? o : x;
    unsigned a = (unsigned)__builtin_amdgcn_readlane((int)x, 0);
    unsigned b = (unsigned)__builtin_amdgcn_readlane((int)x, 16);
    unsigned c = (unsigned)__builtin_amdgcn_readlane((int)x, 32);
    unsigned d = (unsigned)__builtin_amdgcn_readlane((int)x, 48);
    unsigned ab = (a < b) ? a : b, cd = (c < d) ? c : d;
    return (ab < cd) ? ab : cd;
}

// ---------------------------------------------------------------------------
// A2S sequential scan over precomputed scores. One wave per (b,h).
// Lane owns 16 keys: s = 256*jj + 4*lane + i -> float4-coalesced row loads.
// v3: all cross-lane reductions via DPP (VALU) instead of ds_ shuffles.
// Argmin = 3 phases: f32 min-reduce, equality match, u32 index min-reduce
// (equivalent to packed-u64 first-min: same values, smallest index on ties).
// ---------------------------------------------------------------------------
__global__ __launch_bounds__(64) void scan_kernel3(const float* __restrict__ scores,
                                                   unsigned char* __restrict__ keep)
{
    int bh = blockIdx.x;
    int lane = threadIdx.x;
    const float4* A4 = (const float4*)(scores + (size_t)bh * Ss * Ss);
    unsigned char* KP = keep + (size_t)bh * Ss * Ss;
    const float INFv = __int_as_float(0x7f800000);

    float sel[4][4] = {};

    // ---- warmup: select0 = sum_{r=0..CB-1} ff^(CB-1-r) * scores[r]
    {
        float4 nxt[4];
#pragma unroll
        for (int jj = 0; jj < 4; ++jj) nxt[jj] = A4[(size_t)(CBc - 1) * 256 + jj * 64 + lane];
        float wgt = 1.0f;
        for (int r = CBc - 1; r >= 0; --r) {
            float4 a[4];
#pragma unroll
            for (int jj = 0; jj < 4; ++jj) a[jj] = nxt[jj];
            int rp = (r > 0) ? r - 1 : 0;
#pragma unroll
            for (int jj = 0; jj < 4; ++jj) nxt[jj] = A4[(size_t)rp * 256 + jj * 64 + lane];
#pragma unroll
            for (int jj = 0; jj < 4; ++jj) {
                sel[jj][0] = fmaf(wgt, a[jj].x, sel[jj][0]);
                sel[jj][1] = fmaf(wgt, a[jj].y, sel[jj][1]);
                sel[jj][2] = fmaf(wgt, a[jj].z, sel[jj][2]);
                sel[jj][3] = fmaf(wgt, a[jj].w, sel[jj][3]);
            }
            wgt *= FFf;
        }
    }

    unsigned int mbits = 0xFFFFu;

    // ---- main scan, 2-deep prefetch pipeline
    float4 buf0[4], buf1[4];
#pragma unroll
    for (int jj = 0; jj < 4; ++jj) buf0[jj] = A4[(size_t)CBc * 256 + jj * 64 + lane];
#pragma unroll
    for (int jj = 0; jj < 4; ++jj) buf1[jj] = A4[(size_t)(CBc + 1) * 256 + jj * 64 + lane];

    for (int t = CBc; t <= Ss - 2; ++t) {
        float4 a[4];
#pragma unroll
        for (int jj = 0; jj < 4; ++jj) a[jj] = buf0[jj];
#pragma unroll
        for (int jj = 0; jj < 4; ++jj) buf0[jj] = buf1[jj];
        int tp = (t + 2 <= Ss - 1) ? t + 2 : Ss - 1;
#pragma unroll
        for (int jj = 0; jj < 4; ++jj) buf1[jj] = A4[(size_t)tp * 256 + jj * 64 + lane];

        // cur = scores * mask; local sum (association identical to v2)
        float cur[4][4];
        float lsum = 0.0f;
#pragma unroll
        for (int jj = 0; jj < 4; ++jj) {
            cur[jj][0] = ((mbits >> (jj * 4 + 0)) & 1) ? a[jj].x : 0.0f;
            cur[jj][1] = ((mbits >> (jj * 4 + 1)) & 1) ? a[jj].y : 0.0f;
            cur[jj][2] = ((mbits >> (jj * 4 + 2)) & 1) ? a[jj].z : 0.0f;
            cur[jj][3] = ((mbits >> (jj * 4 + 3)) & 1) ? a[jj].w : 0.0f;
            lsum += (cur[jj][0] + cur[jj][1]) + (cur[jj][2] + cur[jj][3]);
        }
        float tot = wave_sum64(lsum);
        float inv = 1.0f / tot;

        // sel update + windowed candidate values
        int local = t - RBc;
        float cand[4][4];
#pragma unroll
        for (int jj = 0; jj < 4; ++jj) {
#pragma unroll
            for (int i = 0; i < 4; ++i) {
                float sv = fmaf(FFf, sel[jj][i], cur[jj][i] * inv);
                sel[jj][i] = sv;
                int s = jj * 256 + lane * 4 + i;
                cand[jj][i] = (s >= SBc && s <= local) ? sv : INFv;
            }
        }
        // phase A: global min value (pairwise local tree, then DPP)
        float m0 = fminf(fminf(cand[0][0], cand[0][1]), fminf(cand[0][2], cand[0][3]));
        float m1 = fminf(fminf(cand[1][0], cand[1][1]), fminf(cand[1][2], cand[1][3]));
        float m2 = fminf(fminf(cand[2][0], cand[2][1]), fminf(cand[2][2], cand[2][3]));
        float m3 = fminf(fminf(cand[3][0], cand[3][1]), fminf(cand[3][2], cand[3][3]));
        float minv = wave_min64f(fminf(fminf(m0, m1), fminf(m2, m3)));

        // phase B: smallest index holding minv (per-lane), phase C: global
        unsigned lidx = 0x7FFFFFFFu;
#pragma unroll
        for (int jj = 0; jj < 4; ++jj)
#pragma unroll
            for (int i = 0; i < 4; ++i) {
                unsigned s = (unsigned)(jj * 256 + lane * 4 + i);
                unsigned c = (cand[jj][i] == minv) ? s : 0x7FFFFFFFu;
                lidx = (c < lidx) ? c : lidx;
            }
        int besti = (int)wave_min64u(lidx);

        // evict (no dynamic register indexing: unrolled compare)
#pragma unroll
        for (int jj = 0; jj < 4; ++jj)
#pragma unroll
            for (int i = 0; i < 4; ++i) {
                int s = jj * 256 + lane * 4 + i;
                if (s == besti) { sel[jj][i] = INFv; mbits &= ~(1u << (jj * 4 + i)); }
            }

        // write keep row t+1
        uchar4* kp4 = (uchar4*)(KP + (size_t)(t + 1) * Ss);
#pragma unroll
        for (int jj = 0; jj < 4; ++jj) {
            uchar4 kb;
            kb.x = (unsigned char)((mbits >> (jj * 4 + 0)) & 1);
            kb.y = (unsigned char)((mbits >> (jj * 4 + 1)) & 1);
            kb.z = (unsigned char)((mbits >> (jj * 4 + 2)) & 1);
            kb.w = (unsigned char)((mbits >> (jj * 4 + 3)) & 1);
            kp4[jj * 64 + lane] = kb;
        }
    }
}

// ---------------------------------------------------------------------------
// Masked renormalization IN PLACE: probs = scores*keep / sum(scores*keep).
// Identical to re-softmaxing the masked logits (same exp terms, same ratio).
// One block per row.
// ---------------------------------------------------------------------------
__global__ __launch_bounds__(256) void renorm_rows(float* __restrict__ scores,
                                                   const unsigned char* __restrict__ keep)
{
    int row = blockIdx.x;          // bh*S + r
    int r = row % Ss;
    float4* a4 = (float4*)(scores + (size_t)row * Ss);
    int tid = threadIdx.x;
    float4 x = a4[tid];
    if (r > CBc) {
        const uchar4* kp = (const uchar4*)(keep + (size_t)row * Ss);
        uchar4 kb = kp[tid];
        if (!kb.x) x.x = 0.0f;
        if (!kb.y) x.y = 0.0f;
        if (!kb.z) x.z = 0.0f;
        if (!kb.w) x.w = 0.0f;
    }
    float s = (x.x + x.y) + (x.z + x.w);
#pragma unroll
    for (int off = 32; off; off >>= 1) s += __shfl_xor(s, off);
    __shared__ float red2[4];
    if ((tid & 63) == 0) red2[tid >> 6] = s;
    __syncthreads();
    float inv = 1.0f / (red2[0] + red2[1] + red2[2] + red2[3]);
    a4[tid] = make_float4(x.x * inv, x.y * inv, x.z * inv, x.w * inv);
}

// ---------------------------------------------------------------------------
// ctx = probs @ v, per (b,h). Output layout [b, s, h*HD+d] for the wo GEMM.
// K-loop causally truncated (probs[sq][k]=0 for k>sq).
// ---------------------------------------------------------------------------
__global__ __launch_bounds__(256) void pv_gemm(const float* __restrict__ probs,
                                               const float* __restrict__ v,
                                               float* __restrict__ ctx)
{
    int bh = blockIdx.z;
    int b_ = bh / NHh, h_ = bh % NHh;
    const float* P = probs + (size_t)bh * Ss * Ss;
    const float* V = v     + (size_t)bh * Ss * HDd;
    int bm = blockIdx.y * 64, bn = blockIdx.x * 64;
    int tid = threadIdx.x, tx = tid & 15, ty = tid >> 4;
    __shared__ float As[16][65];
    __shared__ float Bs[16][64];
    float acc[4][4] = {};
    int kend = bm + 64;  // causal: rows in this tile have no mass beyond bm+63
    for (int k0 = 0; k0 < kend; k0 += 16) {
#pragma unroll
        for (int l = 0; l < 4; ++l) {
            int idx = tid + l * 256;
            int r = idx >> 4, c = idx & 15;
            As[c][r] = P[(size_t)(bm + r) * Ss + k0 + c];
        }
#pragma unroll
        for (int l = 0; l < 4; ++l) {
            int idx = tid + l * 256;
            int r = idx >> 6, c = idx & 63;
            Bs[r][c] = V[(size_t)(k0 + r) * HDd + bn + c];
        }
        __syncthreads();
#pragma unroll
        for (int kk = 0; kk < 16; ++kk) {
            float a[4], b[4];
#pragma unroll
            for (int i = 0; i < 4; ++i) a[i] = As[kk][ty * 4 + i];
#pragma unroll
            for (int j = 0; j < 4; ++j) b[j] = Bs[kk][tx * 4 + j];
#pragma unroll
            for (int i = 0; i < 4; ++i)
#pragma unroll
                for (int j = 0; j < 4; ++j)
                    acc[i][j] = fmaf(a[i], b[j], acc[i][j]);
        }
        __syncthreads();
    }
#pragma unroll
    for (int i = 0; i < 4; ++i) {
        int sq = bm + ty * 4 + i;
#pragma unroll
        for (int j = 0; j < 4; ++j) {
            int d = bn + tx * 4 + j;
            ctx[(size_t)(b_ * Ss + sq) * HIDd + h_ * HDd + d] = acc[i][j];
        }
    }
}

// ---------------------------------------------------------------------------
extern "C" void kernel_launch(void* const* d_in, const int* in_sizes, int n_in,
                              void* d_out, int out_size, void* d_ws, size_t ws_size,
                              hipStream_t stream)
{
    const float* hs = (const float*)d_in[0];
    const float* wq = (const float*)d_in[1];
    const float* wk = (const float*)d_in[2];
    const float* wv = (const float*)d_in[3];
    const float* wo = (const float*)d_in[4];
    float* out = (float*)d_out;

    float* ws = (float*)d_ws;
    size_t off = 0;
    float* q    = ws + off; off += (size_t)NBH * Ss * HDd;   // 4 M floats
    float* k    = ws + off; off += (size_t)NBH * Ss * HDd;
    float* v    = ws + off; off += (size_t)NBH * Ss * HDd;
    float* attn = ws + off; off += (size_t)NBH * Ss * Ss;    // 32 M floats (attn -> scores -> probs)
    float* ctx  = ws + off; off += (size_t)NBH * Ss * HDd;
    unsigned char* keep = (unsigned char*)(ws + off);        // 32 MB u8

    dim3 blk(256);
    dim3 g1(HIDd / 64, (Bb * Ss) / 64);   // 32 x 32

    gemm64x64<1><<<g1, blk, 0, stream>>>(hs, wq, q, Bb * Ss, HIDd, HIDd);
    gemm64x64<1><<<g1, blk, 0, stream>>>(hs, wk, k, Bb * Ss, HIDd, HIDd);
    gemm64x64<1><<<g1, blk, 0, stream>>>(hs, wv, v, Bb * Ss, HIDd, HIDd);

    rope_qk<<<dim3(NBH * Ss), dim3(64), 0, stream>>>(q, k);

    attn_qk<<<dim3(Ss / 64, Ss / 64, NBH), blk, 0, stream>>>(q, k, attn);

    // attn -> scores (normalized softmax probs, causal zeros), in place
    softmax_rows<<<dim3(NROWS), blk, 0, stream>>>(attn);

    scan_kernel3<<<dim3(NBH), dim3(64), 0, stream>>>(attn, keep);

    // scores -> final probs (keep-mask + renormalize), in place
    renorm_rows<<<dim3(NROWS), blk, 0, stream>>>(attn, keep);

    pv_gemm<<<dim3(HDd / 64, Ss / 64, NBH), blk, 0, stream>>>(attn, v, ctx);

    gemm64x64<0><<<g1, blk, 0, stream>>>(ctx, wo, out, Bb * Ss, HIDd, HIDd);
}

// Round 4
// 2270.744 us; speedup vs baseline: 1.8788x; 1.1110x over previous
//
#include <hip/hip_runtime.h>
#include <math.h>

// Problem constants (from reference)
#define Bb    2
#define Ss    1024
#define HIDd  2048
#define NHh   16
#define HDd   128
#define SBc   20      // floor(0.02*1024+0.5)
#define SELBc 61      // floor(0.06*1024+0.5)
#define RBc   82      // floor(0.08*1024+0.5)
#define CBc   163     // SB+SELB+RB
#define FFf   0.9f
#define MASKVAL (-3.4028234663852886e38f)
#define NBH   (Bb*NHh)       // 32
#define NROWS (NBH*Ss)       // 32768

// ---------------------------------------------------------------------------
// Generic 64x64-tile fp32 GEMM, 256 threads, 4x4 micro-tile.
// MODE 0: C[m*N+n] plain row-major.
// MODE 1: qkv permute: m=b*S+s, n=h*HD+d  ->  C[((b*NH+h)*S+s)*HD+d]
// ---------------------------------------------------------------------------
template<int MODE>
__global__ __launch_bounds__(256) void gemm64x64(const float* __restrict__ A,
                                                 const float* __restrict__ Bm,
                                                 float* __restrict__ C,
                                                 int M, int N, int K)
{
    __shared__ float As[16][65];   // [k][m], padded
    __shared__ float Bs[16][64];   // [k][n]
    int tid = threadIdx.x;
    int tx = tid & 15, ty = tid >> 4;
    int bm = blockIdx.y * 64, bn = blockIdx.x * 64;
    float acc[4][4] = {};
    for (int k0 = 0; k0 < K; k0 += 16) {
#pragma unroll
        for (int l = 0; l < 4; ++l) {
            int idx = tid + l * 256;
            int r = idx >> 4, c = idx & 15;
            As[c][r] = A[(size_t)(bm + r) * K + k0 + c];
        }
#pragma unroll
        for (int l = 0; l < 4; ++l) {
            int idx = tid + l * 256;
            int r = idx >> 6, c = idx & 63;
            Bs[r][c] = Bm[(size_t)(k0 + r) * N + bn + c];
        }
        __syncthreads();
#pragma unroll
        for (int kk = 0; kk < 16; ++kk) {
            float a[4], b[4];
#pragma unroll
            for (int i = 0; i < 4; ++i) a[i] = As[kk][ty * 4 + i];
#pragma unroll
            for (int j = 0; j < 4; ++j) b[j] = Bs[kk][tx * 4 + j];
#pragma unroll
            for (int i = 0; i < 4; ++i)
#pragma unroll
                for (int j = 0; j < 4; ++j)
                    acc[i][j] = fmaf(a[i], b[j], acc[i][j]);
        }
        __syncthreads();
    }
#pragma unroll
    for (int i = 0; i < 4; ++i) {
        int m = bm + ty * 4 + i;
#pragma unroll
        for (int j = 0; j < 4; ++j) {
            int n = bn + tx * 4 + j;
            if (MODE == 0) {
                C[(size_t)m * N + n] = acc[i][j];
            } else {
                int b_ = m / Ss, s_ = m % Ss;
                int h_ = n / HDd, d_ = n % HDd;
                C[(size_t)((b_ * NHh + h_) * Ss + s_) * HDd + d_] = acc[i][j];
            }
        }
    }
}

// ---------------------------------------------------------------------------
// RoPE, in-place on q and k. One block per (b,h,s), 64 threads (pair d, d+64).
// ---------------------------------------------------------------------------
__global__ __launch_bounds__(64) void rope_qk(float* __restrict__ q, float* __restrict__ k)
{
    int idx = blockIdx.x;          // bh*S + s
    int s = idx % Ss;
    int d = threadIdx.x;           // 0..63
    float inv = powf(10000.0f, -2.0f * (float)d / 128.0f);
    float fr = (float)s * inv;
    float c = cosf(fr), sn = sinf(fr);
    size_t base = (size_t)idx * HDd;
    float q1 = q[base + d], q2 = q[base + d + 64];
    q[base + d]      = q1 * c - q2 * sn;
    q[base + d + 64] = q2 * c + q1 * sn;
    float k1 = k[base + d], k2 = k[base + d + 64];
    k[base + d]      = k1 * c - k2 * sn;
    k[base + d + 64] = k2 * c + k1 * sn;
}

// ---------------------------------------------------------------------------
// attn = q k^T / sqrt(HD), causal-masked to MASKVAL. 64x64 tiles per (b,h).
// ---------------------------------------------------------------------------
__global__ __launch_bounds__(256) void attn_qk(const float* __restrict__ q,
                                               const float* __restrict__ kmat,
                                               float* __restrict__ attn)
{
    int bh = blockIdx.z;
    int bm = blockIdx.y * 64, bn = blockIdx.x * 64;
    float* out = attn + (size_t)bh * Ss * Ss;
    int tid = threadIdx.x, tx = tid & 15, ty = tid >> 4;

    if (blockIdx.x > blockIdx.y) {  // entire tile above diagonal -> masked
#pragma unroll
        for (int i = 0; i < 4; ++i) {
            int sq = bm + ty * 4 + i;
#pragma unroll
            for (int j = 0; j < 4; ++j) {
                int sk = bn + tx * 4 + j;
                out[(size_t)sq * Ss + sk] = MASKVAL;
            }
        }
        return;
    }
    const float* Q  = q    + (size_t)bh * Ss * HDd;
    const float* Kh = kmat + (size_t)bh * Ss * HDd;
    __shared__ float As[16][65], Ks[16][65];
    float acc[4][4] = {};
    for (int k0 = 0; k0 < HDd; k0 += 16) {
#pragma unroll
        for (int l = 0; l < 4; ++l) {
            int idx = tid + l * 256;
            int r = idx >> 4, c = idx & 15;
            As[c][r] = Q[(size_t)(bm + r) * HDd + k0 + c];
            Ks[c][r] = Kh[(size_t)(bn + r) * HDd + k0 + c];
        }
        __syncthreads();
#pragma unroll
        for (int kk = 0; kk < 16; ++kk) {
            float a[4], b[4];
#pragma unroll
            for (int i = 0; i < 4; ++i) a[i] = As[kk][ty * 4 + i];
#pragma unroll
            for (int j = 0; j < 4; ++j) b[j] = Ks[kk][tx * 4 + j];
#pragma unroll
            for (int i = 0; i < 4; ++i)
#pragma unroll
                for (int j = 0; j < 4; ++j)
                    acc[i][j] = fmaf(a[i], b[j], acc[i][j]);
        }
        __syncthreads();
    }
    const float scale = 0.08838834764831845f;  // 1/sqrt(128)
#pragma unroll
    for (int i = 0; i < 4; ++i) {
        int sq = bm + ty * 4 + i;
#pragma unroll
        for (int j = 0; j < 4; ++j) {
            int sk = bn + tx * 4 + j;
            out[(size_t)sq * Ss + sk] = (sk <= sq) ? acc[i][j] * scale : MASKVAL;
        }
    }
}

// ---------------------------------------------------------------------------
// Row softmax IN PLACE: attn -> scores = exp(a - rowmax) / rowsum.
// One block (256 threads = 4 waves) per row, float4 per thread.
// Masked entries (MASKVAL) become exactly 0.
// ---------------------------------------------------------------------------
__global__ __launch_bounds__(256) void softmax_rows(float* __restrict__ attn)
{
    int row = blockIdx.x;
    float4* a4 = (float4*)(attn + (size_t)row * Ss);
    int tid = threadIdx.x;
    float4 x = a4[tid];
    float m = fmaxf(fmaxf(x.x, x.y), fmaxf(x.z, x.w));
#pragma unroll
    for (int off = 32; off; off >>= 1) m = fmaxf(m, __shfl_xor(m, off));
    __shared__ float red[4];
    if ((tid & 63) == 0) red[tid >> 6] = m;
    __syncthreads();
    float mm = fmaxf(fmaxf(red[0], red[1]), fmaxf(red[2], red[3]));
    float e0 = expf(x.x - mm), e1 = expf(x.y - mm);
    float e2 = expf(x.z - mm), e3 = expf(x.w - mm);
    float s = e0 + e1 + e2 + e3;
#pragma unroll
    for (int off = 32; off; off >>= 1) s += __shfl_xor(s, off);
    __shared__ float red2[4];
    if ((tid & 63) == 0) red2[tid >> 6] = s;
    __syncthreads();
    float inv = 1.0f / (red2[0] + red2[1] + red2[2] + red2[3]);
    a4[tid] = make_float4(e0 * inv, e1 * inv, e2 * inv, e3 * inv);
}

// ---------------------------------------------------------------------------
// DPP cross-lane helpers (VALU-latency, no LDS pipe).
// ---------------------------------------------------------------------------
template<int CTRL>
__device__ __forceinline__ int dpp_i(int x) {
    return __builtin_amdgcn_update_dpp(0, x, CTRL, 0xF, 0xF, true);
}
__device__ __forceinline__ float wave_sum64(float x) {
    x += __int_as_float(dpp_i<0xB1>(__float_as_int(x)));   // quad_perm xor1
    x += __int_as_float(dpp_i<0x4E>(__float_as_int(x)));   // quad_perm xor2
    x += __int_as_float(dpp_i<0x141>(__float_as_int(x)));  // row_half_mirror
    x += __int_as_float(dpp_i<0x140>(__float_as_int(x)));  // row_mirror
    int xi = __float_as_int(x);
    float a = __int_as_float(__builtin_amdgcn_readlane(xi, 0));
    float b = __int_as_float(__builtin_amdgcn_readlane(xi, 16));
    float c = __int_as_float(__builtin_amdgcn_readlane(xi, 32));
    float d = __int_as_float(__builtin_amdgcn_readlane(xi, 48));
    return (a + c) + (b + d);  // matches xor16/xor32 association
}
__device__ __forceinline__ float wave_min64f(float x) {
    x = fminf(x, __int_as_float(dpp_i<0xB1>(__float_as_int(x))));
    x = fminf(x, __int_as_float(dpp_i<0x4E>(__float_as_int(x))));
    x = fminf(x, __int_as_float(dpp_i<0x141>(__float_as_int(x))));
    x = fminf(x, __int_as_float(dpp_i<0x140>(__float_as_int(x))));
    int xi = __float_as_int(x);
    float a = __int_as_float(__builtin_amdgcn_readlane(xi, 0));
    float b = __int_as_float(__builtin_amdgcn_readlane(xi, 16));
    float c = __int_as_float(__builtin_amdgcn_readlane(xi, 32));
    float d = __int_as_float(__builtin_amdgcn_readlane(xi, 48));
    return fminf(fminf(a, b), fminf(c, d));
}
__device__ __forceinline__ unsigned wave_min64u(unsigned x) {
    unsigned o;
    o = (unsigned)dpp_i<0xB1>((int)x);  x = (o < x) ? o : x;
    o = (unsigned)dpp_i<0x4E>((int)x);  x = (o < x) ? o : x;
    o = (unsigned)dpp_i<0x141>((int)x); x = (o < x) ? o : x;
    o = (unsigned)dpp_i<0x140>((int)x); x = (o < x) ? o : x;
    unsigned a = (unsigned)__builtin_amdgcn_readlane((int)x, 0);
    unsigned b = (unsigned)__builtin_amdgcn_readlane((int)x, 16);
    unsigned c = (unsigned)__builtin_amdgcn_readlane((int)x, 32);
    unsigned d = (unsigned)__builtin_amdgcn_readlane((int)x, 48);
    unsigned ab = (a < b) ? a : b, cd = (c < d) ? c : d;
    return (ab < cd) ? ab : cd;
}

// ---------------------------------------------------------------------------
// A2S sequential scan over precomputed scores. One wave per (b,h).
// Lane owns 16 keys: s = 256*jj + 4*lane + i -> float4-coalesced row loads.
// v4: depth-4 software pipeline with 4 statically-named register row-buffers
// (unroll-by-4, 860 = 4*215). A row's load is issued 4 steps before its use,
// so ~2000 cyc of chain compute covers the ~900 cyc HBM/LLC latency; each
// buffer is a distinct register set so the compiler can use partial vmcnt
// waits (no register-copy pipeline hazard like v2/v3).
// Warmup uses Horner recurrence sel = ff*sel + score (same value, ascending).
// ---------------------------------------------------------------------------
__global__ __launch_bounds__(64) void scan_kernel4(const float* __restrict__ scores,
                                                   unsigned char* __restrict__ keep)
{
    int bh = blockIdx.x;
    int lane = threadIdx.x;
    const float4* A4 = (const float4*)(scores + (size_t)bh * Ss * Ss);
    unsigned char* KP = keep + (size_t)bh * Ss * Ss;
    const float INFv = __int_as_float(0x7f800000);

    float sel[4][4] = {};
    float4 r0[4], r1[4], r2[4], r3[4];

#define LOADROW(RB, ROW)                                                     \
    do {                                                                     \
        size_t _base = (size_t)(ROW) * 256 + lane;                           \
        RB[0] = A4[_base];       RB[1] = A4[_base + 64];                     \
        RB[2] = A4[_base + 128]; RB[3] = A4[_base + 192];                    \
    } while (0)

    // ---- warmup (Horner, ascending): sel_r = ff*sel_{r-1} + scores[r]
#define WARM_STEP(RB, NEXTROW)                                               \
    do {                                                                     \
        float4 _a[4];                                                        \
        _a[0] = RB[0]; _a[1] = RB[1]; _a[2] = RB[2]; _a[3] = RB[3];          \
        LOADROW(RB, NEXTROW);                                                \
        _Pragma("unroll")                                                    \
        for (int jj = 0; jj < 4; ++jj) {                                     \
            sel[jj][0] = fmaf(FFf, sel[jj][0], _a[jj].x);                    \
            sel[jj][1] = fmaf(FFf, sel[jj][1], _a[jj].y);                    \
            sel[jj][2] = fmaf(FFf, sel[jj][2], _a[jj].z);                    \
            sel[jj][3] = fmaf(FFf, sel[jj][3], _a[jj].w);                    \
        }                                                                    \
    } while (0)

    LOADROW(r0, 0); LOADROW(r1, 1); LOADROW(r2, 2); LOADROW(r3, 3);
    for (int r = 0; r < 160; r += 4) {     // rows 0..159, loads rows 4..163
        WARM_STEP(r0, r + 4);
        WARM_STEP(r1, r + 5);
        WARM_STEP(r2, r + 6);
        WARM_STEP(r3, r + 7);
    }
    // tail rows 160..162 (already in r0..r2; r3 holds row 163 but reload below)
    {
        float4 tl[3][4];
#pragma unroll
        for (int jj = 0; jj < 4; ++jj) { tl[0][jj] = r0[jj]; tl[1][jj] = r1[jj]; tl[2][jj] = r2[jj]; }
#pragma unroll
        for (int u = 0; u < 3; ++u)
#pragma unroll
            for (int jj = 0; jj < 4; ++jj) {
                sel[jj][0] = fmaf(FFf, sel[jj][0], tl[u][jj].x);
                sel[jj][1] = fmaf(FFf, sel[jj][1], tl[u][jj].y);
                sel[jj][2] = fmaf(FFf, sel[jj][2], tl[u][jj].z);
                sel[jj][3] = fmaf(FFf, sel[jj][3], tl[u][jj].w);
            }
    }

    unsigned int mbits = 0xFFFFu;

    // ---- main scan: rows CBc..Ss-2, depth-4 pipeline
    LOADROW(r0, CBc);     LOADROW(r1, CBc + 1);
    LOADROW(r2, CBc + 2); LOADROW(r3, CBc + 3);

#define SCAN_STEP(RB, T)                                                     \
    do {                                                                     \
        const int _t = (T);                                                  \
        float cur[4][4];                                                     \
        float lsum = 0.0f;                                                   \
        _Pragma("unroll")                                                    \
        for (int jj = 0; jj < 4; ++jj) {                                     \
            cur[jj][0] = ((mbits >> (jj * 4 + 0)) & 1) ? RB[jj].x : 0.0f;    \
            cur[jj][1] = ((mbits >> (jj * 4 + 1)) & 1) ? RB[jj].y : 0.0f;    \
            cur[jj][2] = ((mbits >> (jj * 4 + 2)) & 1) ? RB[jj].z : 0.0f;    \
            cur[jj][3] = ((mbits >> (jj * 4 + 3)) & 1) ? RB[jj].w : 0.0f;    \
            lsum += (cur[jj][0] + cur[jj][1]) + (cur[jj][2] + cur[jj][3]);   \
        }                                                                    \
        int _tp = _t + 4; if (_tp > Ss - 1) _tp = Ss - 1;                    \
        LOADROW(RB, _tp);                                                    \
        float tot = wave_sum64(lsum);                                        \
        float inv = 1.0f / tot;                                              \
        int local = _t - RBc;                                                \
        float cand[4][4];                                                    \
        _Pragma("unroll")                                                    \
        for (int jj = 0; jj < 4; ++jj) {                                     \
            _Pragma("unroll")                                                \
            for (int i = 0; i < 4; ++i) {                                    \
                float sv = fmaf(FFf, sel[jj][i], cur[jj][i] * inv);          \
                sel[jj][i] = sv;                                             \
                int s = jj * 256 + lane * 4 + i;                             \
                cand[jj][i] = (s >= SBc && s <= local) ? sv : INFv;          \
            }                                                                \
        }                                                                    \
        float m0 = fminf(fminf(cand[0][0], cand[0][1]), fminf(cand[0][2], cand[0][3])); \
        float m1 = fminf(fminf(cand[1][0], cand[1][1]), fminf(cand[1][2], cand[1][3])); \
        float m2 = fminf(fminf(cand[2][0], cand[2][1]), fminf(cand[2][2], cand[2][3])); \
        float m3 = fminf(fminf(cand[3][0], cand[3][1]), fminf(cand[3][2], cand[3][3])); \
        float minv = wave_min64f(fminf(fminf(m0, m1), fminf(m2, m3)));       \
        unsigned lidx = 0x7FFFFFFFu;                                         \
        _Pragma("unroll")                                                    \
        for (int jj = 0; jj < 4; ++jj)                                       \
            _Pragma("unroll")                                                \
            for (int i = 0; i < 4; ++i) {                                    \
                unsigned s = (unsigned)(jj * 256 + lane * 4 + i);            \
                unsigned c = (cand[jj][i] == minv) ? s : 0x7FFFFFFFu;        \
                lidx = (c < lidx) ? c : lidx;                                \
            }                                                                \
        int besti = (int)wave_min64u(lidx);                                  \
        _Pragma("unroll")                                                    \
        for (int jj = 0; jj < 4; ++jj)                                       \
            _Pragma("unroll")                                                \
            for (int i = 0; i < 4; ++i) {                                    \
                int s = jj * 256 + lane * 4 + i;                             \
                if (s == besti) { sel[jj][i] = INFv; mbits &= ~(1u << (jj * 4 + i)); } \
            }                                                                \
        uchar4* kp4 = (uchar4*)(KP + (size_t)(_t + 1) * Ss);                 \
        _Pragma("unroll")                                                    \
        for (int jj = 0; jj < 4; ++jj) {                                     \
            uchar4 kb;                                                       \
            kb.x = (unsigned char)((mbits >> (jj * 4 + 0)) & 1);             \
            kb.y = (unsigned char)((mbits >> (jj * 4 + 1)) & 1);             \
            kb.z = (unsigned char)((mbits >> (jj * 4 + 2)) & 1);             \
            kb.w = (unsigned char)((mbits >> (jj * 4 + 3)) & 1);             \
            kp4[jj * 64 + lane] = kb;                                        \
        }                                                                    \
    } while (0)

    for (int t0 = CBc; t0 <= Ss - 2; t0 += 4) {   // 860 rows = 215 groups
        SCAN_STEP(r0, t0 + 0);
        SCAN_STEP(r1, t0 + 1);
        SCAN_STEP(r2, t0 + 2);
        SCAN_STEP(r3, t0 + 3);
    }
#undef SCAN_STEP
#undef WARM_STEP
#undef LOADROW
}

// ---------------------------------------------------------------------------
// Masked renormalization IN PLACE: probs = scores*keep / sum(scores*keep).
// ---------------------------------------------------------------------------
__global__ __launch_bounds__(256) void renorm_rows(float* __restrict__ scores,
                                                   const unsigned char* __restrict__ keep)
{
    int row = blockIdx.x;          // bh*S + r
    int r = row % Ss;
    float4* a4 = (float4*)(scores + (size_t)row * Ss);
    int tid = threadIdx.x;
    float4 x = a4[tid];
    if (r > CBc) {
        const uchar4* kp = (const uchar4*)(keep + (size_t)row * Ss);
        uchar4 kb = kp[tid];
        if (!kb.x) x.x = 0.0f;
        if (!kb.y) x.y = 0.0f;
        if (!kb.z) x.z = 0.0f;
        if (!kb.w) x.w = 0.0f;
    }
    float s = (x.x + x.y) + (x.z + x.w);
#pragma unroll
    for (int off = 32; off; off >>= 1) s += __shfl_xor(s, off);
    __shared__ float red2[4];
    if ((tid & 63) == 0) red2[tid >> 6] = s;
    __syncthreads();
    float inv = 1.0f / (red2[0] + red2[1] + red2[2] + red2[3]);
    a4[tid] = make_float4(x.x * inv, x.y * inv, x.z * inv, x.w * inv);
}

// ---------------------------------------------------------------------------
// ctx = probs @ v, per (b,h). Output layout [b, s, h*HD+d] for the wo GEMM.
// ---------------------------------------------------------------------------
__global__ __launch_bounds__(256) void pv_gemm(const float* __restrict__ probs,
                                               const float* __restrict__ v,
                                               float* __restrict__ ctx)
{
    int bh = blockIdx.z;
    int b_ = bh / NHh, h_ = bh % NHh;
    const float* P = probs + (size_t)bh * Ss * Ss;
    const float* V = v     + (size_t)bh * Ss * HDd;
    int bm = blockIdx.y * 64, bn = blockIdx.x * 64;
    int tid = threadIdx.x, tx = tid & 15, ty = tid >> 4;
    __shared__ float As[16][65];
    __shared__ float Bs[16][64];
    float acc[4][4] = {};
    int kend = bm + 64;  // causal truncation
    for (int k0 = 0; k0 < kend; k0 += 16) {
#pragma unroll
        for (int l = 0; l < 4; ++l) {
            int idx = tid + l * 256;
            int r = idx >> 4, c = idx & 15;
            As[c][r] = P[(size_t)(bm + r) * Ss + k0 + c];
        }
#pragma unroll
        for (int l = 0; l < 4; ++l) {
            int idx = tid + l * 256;
            int r = idx >> 6, c = idx & 63;
            Bs[r][c] = V[(size_t)(k0 + r) * HDd + bn + c];
        }
        __syncthreads();
#pragma unroll
        for (int kk = 0; kk < 16; ++kk) {
            float a[4], b[4];
#pragma unroll
            for (int i = 0; i < 4; ++i) a[i] = As[kk][ty * 4 + i];
#pragma unroll
            for (int j = 0; j < 4; ++j) b[j] = Bs[kk][tx * 4 + j];
#pragma unroll
            for (int i = 0; i < 4; ++i)
#pragma unroll
                for (int j = 0; j < 4; ++j)
                    acc[i][j] = fmaf(a[i], b[j], acc[i][j]);
        }
        __syncthreads();
    }
#pragma unroll
    for (int i = 0; i < 4; ++i) {
        int sq = bm + ty * 4 + i;
#pragma unroll
        for (int j = 0; j < 4; ++j) {
            int d = bn + tx * 4 + j;
            ctx[(size_t)(b_ * Ss + sq) * HIDd + h_ * HDd + d] = acc[i][j];
        }
    }
}

// ---------------------------------------------------------------------------
extern "C" void kernel_launch(void* const* d_in, const int* in_sizes, int n_in,
                              void* d_out, int out_size, void* d_ws, size_t ws_size,
                              hipStream_t stream)
{
    const float* hs = (const float*)d_in[0];
    const float* wq = (const float*)d_in[1];
    const float* wk = (const float*)d_in[2];
    const float* wv = (const float*)d_in[3];
    const float* wo = (const float*)d_in[4];
    float* out = (float*)d_out;

    float* ws = (float*)d_ws;
    size_t off = 0;
    float* q    = ws + off; off += (size_t)NBH * Ss * HDd;   // 4 M floats
    float* k    = ws + off; off += (size_t)NBH * Ss * HDd;
    float* v    = ws + off; off += (size_t)NBH * Ss * HDd;
    float* attn = ws + off; off += (size_t)NBH * Ss * Ss;    // attn -> scores -> probs
    float* ctx  = ws + off; off += (size_t)NBH * Ss * HDd;
    unsigned char* keep = (unsigned char*)(ws + off);        // 32 MB u8

    dim3 blk(256);
    dim3 g1(HIDd / 64, (Bb * Ss) / 64);   // 32 x 32

    gemm64x64<1><<<g1, blk, 0, stream>>>(hs, wq, q, Bb * Ss, HIDd, HIDd);
    gemm64x64<1><<<g1, blk, 0, stream>>>(hs, wk, k, Bb * Ss, HIDd, HIDd);
    gemm64x64<1><<<g1, blk, 0, stream>>>(hs, wv, v, Bb * Ss, HIDd, HIDd);

    rope_qk<<<dim3(NBH * Ss), dim3(64), 0, stream>>>(q, k);

    attn_qk<<<dim3(Ss / 64, Ss / 64, NBH), blk, 0, stream>>>(q, k, attn);

    softmax_rows<<<dim3(NROWS), blk, 0, stream>>>(attn);

    scan_kernel4<<<dim3(NBH), dim3(64), 0, stream>>>(attn, keep);

    renorm_rows<<<dim3(NROWS), blk, 0, stream>>>(attn, keep);

    pv_gemm<<<dim3(HDd / 64, Ss / 64, NBH), blk, 0, stream>>>(attn, v, ctx);

    gemm64x64<0><<<g1, blk, 0, stream>>>(ctx, wo, out, Bb * Ss, HIDd, HIDd);
}

// Round 6
// 1284.112 us; speedup vs baseline: 3.3223x; 1.7683x over previous
//
#include <hip/hip_runtime.h>
#include <math.h>

// Problem constants (from reference)
#define Bb    2
#define Ss    1024
#define HIDd  2048
#define NHh   16
#define HDd   128
#define SBc   20      // floor(0.02*1024+0.5)
#define SELBc 61      // floor(0.06*1024+0.5)
#define RBc   82      // floor(0.08*1024+0.5)
#define CBc   163     // SB+SELB+RB
#define FFf   0.9f
#define MASKVAL (-3.4028234663852886e38f)
#define NBH   (Bb*NHh)       // 32
#define NROWS (NBH*Ss)       // 32768

typedef __attribute__((ext_vector_type(8))) short short8;
typedef __attribute__((ext_vector_type(4))) float f32x4;

__device__ __forceinline__ unsigned short f2b(float f) {
    unsigned u = __float_as_uint(f);
    u = (u + 0x7FFFu + ((u >> 16) & 1u)) >> 16;   // RNE
    return (unsigned short)u;
}
__device__ __forceinline__ float b2f(unsigned short h) {
    return __uint_as_float((unsigned)h << 16);
}

// ---------------------------------------------------------------------------
// fp32 -> split bf16 (hi + lo). lo = bf16(x - fp32(hi)).
// ---------------------------------------------------------------------------
__global__ __launch_bounds__(256) void conv_split(const float* __restrict__ x,
                                                  unsigned short* __restrict__ yh,
                                                  unsigned short* __restrict__ yl, int n4)
{
    int i = blockIdx.x * 256 + threadIdx.x;
    if (i >= n4) return;
    float4 v = ((const float4*)x)[i];
    ushort4 h, l;
    h.x = f2b(v.x); l.x = f2b(v.x - b2f(h.x));
    h.y = f2b(v.y); l.y = f2b(v.y - b2f(h.y));
    h.z = f2b(v.z); l.z = f2b(v.z - b2f(h.z));
    h.w = f2b(v.w); l.w = f2b(v.w - b2f(h.w));
    ((ushort4*)yh)[i] = h;
    ((ushort4*)yl)[i] = l;
}

// ---------------------------------------------------------------------------
// Transpose + convert: W[k][n] fp32 -> Wt[n][k] bf16 (single).
// ---------------------------------------------------------------------------
__global__ __launch_bounds__(256) void tconv(const float* __restrict__ W,
                                             unsigned short* __restrict__ Wt,
                                             int Kdim, int Ndim)
{
    __shared__ float T[64][65];
    int n0 = blockIdx.x * 64, k0 = blockIdx.y * 64;
    int tid = threadIdx.x;
    int rr = tid >> 4, cc = (tid & 15) * 4;
#pragma unroll
    for (int p = 0; p < 4; ++p) {
        int r = rr + p * 16;
        float4 x = *(const float4*)&W[(size_t)(k0 + r) * Ndim + n0 + cc];
        T[r][cc] = x.x; T[r][cc + 1] = x.y; T[r][cc + 2] = x.z; T[r][cc + 3] = x.w;
    }
    __syncthreads();
#pragma unroll
    for (int p = 0; p < 4; ++p) {
        int rn = rr + p * 16;
        ushort4 o;
        o.x = f2b(T[cc][rn]);     o.y = f2b(T[cc + 1][rn]);
        o.z = f2b(T[cc + 2][rn]); o.w = f2b(T[cc + 3][rn]);
        *(ushort4*)&Wt[(size_t)(n0 + rn) * Kdim + k0 + cc] = o;
    }
}

// ---------------------------------------------------------------------------
// Transpose + split convert: W[k][n] fp32 -> Wth/Wtl[n][k] bf16 hi/lo.
// ---------------------------------------------------------------------------
__global__ __launch_bounds__(256) void tconv_split(const float* __restrict__ W,
                                                   unsigned short* __restrict__ Wth,
                                                   unsigned short* __restrict__ Wtl,
                                                   int Kdim, int Ndim)
{
    __shared__ float T[64][65];
    int n0 = blockIdx.x * 64, k0 = blockIdx.y * 64;
    int tid = threadIdx.x;
    int rr = tid >> 4, cc = (tid & 15) * 4;
#pragma unroll
    for (int p = 0; p < 4; ++p) {
        int r = rr + p * 16;
        float4 x = *(const float4*)&W[(size_t)(k0 + r) * Ndim + n0 + cc];
        T[r][cc] = x.x; T[r][cc + 1] = x.y; T[r][cc + 2] = x.z; T[r][cc + 3] = x.w;
    }
    __syncthreads();
#pragma unroll
    for (int p = 0; p < 4; ++p) {
        int rn = rr + p * 16;
        float v0 = T[cc][rn], v1 = T[cc + 1][rn], v2 = T[cc + 2][rn], v3 = T[cc + 3][rn];
        ushort4 h, l;
        h.x = f2b(v0); l.x = f2b(v0 - b2f(h.x));
        h.y = f2b(v1); l.y = f2b(v1 - b2f(h.y));
        h.z = f2b(v2); l.z = f2b(v2 - b2f(h.z));
        h.w = f2b(v3); l.w = f2b(v3 - b2f(h.w));
        *(ushort4*)&Wth[(size_t)(n0 + rn) * Kdim + k0 + cc] = h;
        *(ushort4*)&Wtl[(size_t)(n0 + rn) * Kdim + k0 + cc] = l;
    }
}

// ---------------------------------------------------------------------------
// Single-bf16 MFMA GEMM: C = A @ Bt^T. 128x128 tile, 4 waves, 4x4 frags.
// MODE 0: C[m*N+n].  MODE 1: qkv permute -> C[((b*NH+h)*S+s)*HD+d].
// ---------------------------------------------------------------------------
template<int MODE>
__global__ __launch_bounds__(256) void gemm_bf16t(const unsigned short* __restrict__ A,
                                                  const unsigned short* __restrict__ Bt,
                                                  float* __restrict__ C,
                                                  int M, int N, int K)
{
    __shared__ unsigned short As[128 * 32];
    __shared__ unsigned short Bs[128 * 32];
    const int tid = threadIdx.x;
    const int bm = blockIdx.y * 128, bn = blockIdx.x * 128;
    const int lane = tid & 63, wid = tid >> 6;
    const int wr = (wid >> 1) * 64, wc = (wid & 1) * 64;
    const int lm = lane & 15, lk = (lane >> 4) * 8;

    f32x4 acc[4][4];
#pragma unroll
    for (int mi = 0; mi < 4; ++mi)
#pragma unroll
        for (int ni = 0; ni < 4; ++ni) acc[mi][ni] = 0.0f;

    for (int k0 = 0; k0 < K; k0 += 32) {
#pragma unroll
        for (int l = 0; l < 2; ++l) {
            int L = tid + l * 256;
            int row = L >> 2, c8 = (L & 3) * 8;
            *(short8*)&As[row * 32 + c8] = *(const short8*)&A[(size_t)(bm + row) * K + k0 + c8];
            *(short8*)&Bs[row * 32 + c8] = *(const short8*)&Bt[(size_t)(bn + row) * K + k0 + c8];
        }
        __syncthreads();
        short8 af[4], bf[4];
#pragma unroll
        for (int mi = 0; mi < 4; ++mi) af[mi] = *(short8*)&As[(wr + mi * 16 + lm) * 32 + lk];
#pragma unroll
        for (int ni = 0; ni < 4; ++ni) bf[ni] = *(short8*)&Bs[(wc + ni * 16 + lm) * 32 + lk];
#pragma unroll
        for (int mi = 0; mi < 4; ++mi)
#pragma unroll
            for (int ni = 0; ni < 4; ++ni)
                acc[mi][ni] = __builtin_amdgcn_mfma_f32_16x16x32_bf16(af[mi], bf[ni], acc[mi][ni], 0, 0, 0);
        __syncthreads();
    }
    const int lr = (lane >> 4) * 4;  // C/D: col=lane&15, row=(lane>>4)*4+reg
#pragma unroll
    for (int mi = 0; mi < 4; ++mi)
#pragma unroll
        for (int ni = 0; ni < 4; ++ni)
#pragma unroll
            for (int r = 0; r < 4; ++r) {
                int m = bm + wr + mi * 16 + lr + r;
                int n = bn + wc + ni * 16 + lm;
                float vv = acc[mi][ni][r];
                if (MODE == 0) {
                    C[(size_t)m * N + n] = vv;
                } else {
                    int b_ = m / Ss, s_ = m % Ss;
                    int h_ = n / HDd, d_ = n % HDd;
                    C[(size_t)((b_ * NHh + h_) * Ss + s_) * HDd + d_] = vv;
                }
            }
}

// ---------------------------------------------------------------------------
// Split-bf16 MFMA GEMM (hi/lo): C = (Ah+Al) @ (Bh+Bl)^T, dropping Al*Bl.
// 3 MFMAs per fragment pair: ah*bh + ah*bl + al*bh. ~fp32-grade precision.
// ---------------------------------------------------------------------------
template<int MODE>
__global__ __launch_bounds__(256) void gemm_split(const unsigned short* __restrict__ Ah,
                                                  const unsigned short* __restrict__ Al,
                                                  const unsigned short* __restrict__ Bh,
                                                  const unsigned short* __restrict__ Bl,
                                                  float* __restrict__ C,
                                                  int M, int N, int K)
{
    __shared__ unsigned short AsH[128 * 32], AsL[128 * 32];
    __shared__ unsigned short BsH[128 * 32], BsL[128 * 32];
    const int tid = threadIdx.x;
    const int bm = blockIdx.y * 128, bn = blockIdx.x * 128;
    const int lane = tid & 63, wid = tid >> 6;
    const int wr = (wid >> 1) * 64, wc = (wid & 1) * 64;
    const int lm = lane & 15, lk = (lane >> 4) * 8;

    f32x4 acc[4][4];
#pragma unroll
    for (int mi = 0; mi < 4; ++mi)
#pragma unroll
        for (int ni = 0; ni < 4; ++ni) acc[mi][ni] = 0.0f;

    for (int k0 = 0; k0 < K; k0 += 32) {
#pragma unroll
        for (int l = 0; l < 2; ++l) {
            int L = tid + l * 256;
            int row = L >> 2, c8 = (L & 3) * 8;
            size_t ga = (size_t)(bm + row) * K + k0 + c8;
            size_t gb = (size_t)(bn + row) * K + k0 + c8;
            *(short8*)&AsH[row * 32 + c8] = *(const short8*)&Ah[ga];
            *(short8*)&AsL[row * 32 + c8] = *(const short8*)&Al[ga];
            *(short8*)&BsH[row * 32 + c8] = *(const short8*)&Bh[gb];
            *(short8*)&BsL[row * 32 + c8] = *(const short8*)&Bl[gb];
        }
        __syncthreads();
        short8 ah[4], al[4], bh[4], bl[4];
#pragma unroll
        for (int mi = 0; mi < 4; ++mi) {
            ah[mi] = *(short8*)&AsH[(wr + mi * 16 + lm) * 32 + lk];
            al[mi] = *(short8*)&AsL[(wr + mi * 16 + lm) * 32 + lk];
        }
#pragma unroll
        for (int ni = 0; ni < 4; ++ni) {
            bh[ni] = *(short8*)&BsH[(wc + ni * 16 + lm) * 32 + lk];
            bl[ni] = *(short8*)&BsL[(wc + ni * 16 + lm) * 32 + lk];
        }
#pragma unroll
        for (int mi = 0; mi < 4; ++mi)
#pragma unroll
            for (int ni = 0; ni < 4; ++ni) {
                acc[mi][ni] = __builtin_amdgcn_mfma_f32_16x16x32_bf16(ah[mi], bh[ni], acc[mi][ni], 0, 0, 0);
                acc[mi][ni] = __builtin_amdgcn_mfma_f32_16x16x32_bf16(ah[mi], bl[ni], acc[mi][ni], 0, 0, 0);
                acc[mi][ni] = __builtin_amdgcn_mfma_f32_16x16x32_bf16(al[mi], bh[ni], acc[mi][ni], 0, 0, 0);
            }
        __syncthreads();
    }
    const int lr = (lane >> 4) * 4;
#pragma unroll
    for (int mi = 0; mi < 4; ++mi)
#pragma unroll
        for (int ni = 0; ni < 4; ++ni)
#pragma unroll
            for (int r = 0; r < 4; ++r) {
                int m = bm + wr + mi * 16 + lr + r;
                int n = bn + wc + ni * 16 + lm;
                float vv = acc[mi][ni][r];
                if (MODE == 0) {
                    C[(size_t)m * N + n] = vv;
                } else {
                    int b_ = m / Ss, s_ = m % Ss;
                    int h_ = n / HDd, d_ = n % HDd;
                    C[(size_t)((b_ * NHh + h_) * Ss + s_) * HDd + d_] = vv;
                }
            }
}

// ---------------------------------------------------------------------------
// RoPE (fp32 math) -> split bf16 q,k (hi/lo).
// ---------------------------------------------------------------------------
__global__ __launch_bounds__(64) void rope_qk_split(const float* __restrict__ q,
                                                    const float* __restrict__ k,
                                                    unsigned short* __restrict__ qh,
                                                    unsigned short* __restrict__ ql,
                                                    unsigned short* __restrict__ kh,
                                                    unsigned short* __restrict__ kl)
{
    int idx = blockIdx.x;          // bh*S + s
    int s = idx % Ss;
    int d = threadIdx.x;           // 0..63
    float inv = powf(10000.0f, -2.0f * (float)d / 128.0f);
    float fr = (float)s * inv;
    float c = cosf(fr), sn = sinf(fr);
    size_t base = (size_t)idx * HDd;
    float q1 = q[base + d], q2 = q[base + d + 64];
    float k1 = k[base + d], k2 = k[base + d + 64];
    float qa = q1 * c - q2 * sn, qbv = q2 * c + q1 * sn;
    float ka = k1 * c - k2 * sn, kbv = k2 * c + k1 * sn;
    unsigned short h;
    h = f2b(qa);  qh[base + d]      = h; ql[base + d]      = f2b(qa  - b2f(h));
    h = f2b(qbv); qh[base + d + 64] = h; ql[base + d + 64] = f2b(qbv - b2f(h));
    h = f2b(ka);  kh[base + d]      = h; kl[base + d]      = f2b(ka  - b2f(h));
    h = f2b(kbv); kh[base + d + 64] = h; kl[base + d + 64] = f2b(kbv - b2f(h));
}

// ---------------------------------------------------------------------------
// attn = q k^T / sqrt(HD) via split-bf16 MFMA, causal mask to MASKVAL.
// ---------------------------------------------------------------------------
__global__ __launch_bounds__(256) void attn_qk_split(const unsigned short* __restrict__ qh,
                                                     const unsigned short* __restrict__ ql,
                                                     const unsigned short* __restrict__ kh,
                                                     const unsigned short* __restrict__ kl,
                                                     float* __restrict__ attn)
{
    const int bh = blockIdx.z;
    const int bm = blockIdx.y * 128, bn = blockIdx.x * 128;
    float* C = attn + (size_t)bh * Ss * Ss;
    const int tid = threadIdx.x;

    if (blockIdx.x > blockIdx.y) {  // fully above diagonal
        float4 mv = make_float4(MASKVAL, MASKVAL, MASKVAL, MASKVAL);
#pragma unroll
        for (int i = 0; i < 16; ++i) {
            int L = tid + i * 256;
            int row = L >> 5, c4 = (L & 31) * 4;
            *(float4*)&C[(size_t)(bm + row) * Ss + bn + c4] = mv;
        }
        return;
    }
    const size_t hb = (size_t)bh * Ss * HDd;
    const unsigned short* Ah = qh + hb;
    const unsigned short* Al = ql + hb;
    const unsigned short* Bh = kh + hb;
    const unsigned short* Bl = kl + hb;

    __shared__ unsigned short AsH[128 * 32], AsL[128 * 32];
    __shared__ unsigned short BsH[128 * 32], BsL[128 * 32];
    const int lane = tid & 63, wid = tid >> 6;
    const int wr = (wid >> 1) * 64, wc = (wid & 1) * 64;
    const int lm = lane & 15, lk = (lane >> 4) * 8;

    f32x4 acc[4][4];
#pragma unroll
    for (int mi = 0; mi < 4; ++mi)
#pragma unroll
        for (int ni = 0; ni < 4; ++ni) acc[mi][ni] = 0.0f;

    for (int k0 = 0; k0 < HDd; k0 += 32) {
#pragma unroll
        for (int l = 0; l < 2; ++l) {
            int L = tid + l * 256;
            int row = L >> 2, c8 = (L & 3) * 8;
            size_t ga = (size_t)(bm + row) * HDd + k0 + c8;
            size_t gb = (size_t)(bn + row) * HDd + k0 + c8;
            *(short8*)&AsH[row * 32 + c8] = *(const short8*)&Ah[ga];
            *(short8*)&AsL[row * 32 + c8] = *(const short8*)&Al[ga];
            *(short8*)&BsH[row * 32 + c8] = *(const short8*)&Bh[gb];
            *(short8*)&BsL[row * 32 + c8] = *(const short8*)&Bl[gb];
        }
        __syncthreads();
        short8 ah[4], al[4], bh2[4], bl2[4];
#pragma unroll
        for (int mi = 0; mi < 4; ++mi) {
            ah[mi] = *(short8*)&AsH[(wr + mi * 16 + lm) * 32 + lk];
            al[mi] = *(short8*)&AsL[(wr + mi * 16 + lm) * 32 + lk];
        }
#pragma unroll
        for (int ni = 0; ni < 4; ++ni) {
            bh2[ni] = *(short8*)&BsH[(wc + ni * 16 + lm) * 32 + lk];
            bl2[ni] = *(short8*)&BsL[(wc + ni * 16 + lm) * 32 + lk];
        }
#pragma unroll
        for (int mi = 0; mi < 4; ++mi)
#pragma unroll
            for (int ni = 0; ni < 4; ++ni) {
                acc[mi][ni] = __builtin_amdgcn_mfma_f32_16x16x32_bf16(ah[mi], bh2[ni], acc[mi][ni], 0, 0, 0);
                acc[mi][ni] = __builtin_amdgcn_mfma_f32_16x16x32_bf16(ah[mi], bl2[ni], acc[mi][ni], 0, 0, 0);
                acc[mi][ni] = __builtin_amdgcn_mfma_f32_16x16x32_bf16(al[mi], bh2[ni], acc[mi][ni], 0, 0, 0);
            }
        __syncthreads();
    }
    const float scale = 0.08838834764831845f;  // 1/sqrt(128)
    const int lr = (lane >> 4) * 4;
#pragma unroll
    for (int mi = 0; mi < 4; ++mi)
#pragma unroll
        for (int ni = 0; ni < 4; ++ni)
#pragma unroll
            for (int r = 0; r < 4; ++r) {
                int sq = bm + wr + mi * 16 + lr + r;
                int sk = bn + wc + ni * 16 + lm;
                C[(size_t)sq * Ss + sk] = (sk <= sq) ? acc[mi][ni][r] * scale : MASKVAL;
            }
}

// ---------------------------------------------------------------------------
// Row softmax IN PLACE: attn -> scores = exp(a - rowmax) / rowsum.
// ---------------------------------------------------------------------------
__global__ __launch_bounds__(256) void softmax_rows(float* __restrict__ attn)
{
    int row = blockIdx.x;
    float4* a4 = (float4*)(attn + (size_t)row * Ss);
    int tid = threadIdx.x;
    float4 x = a4[tid];
    float m = fmaxf(fmaxf(x.x, x.y), fmaxf(x.z, x.w));
#pragma unroll
    for (int off = 32; off; off >>= 1) m = fmaxf(m, __shfl_xor(m, off));
    __shared__ float red[4];
    if ((tid & 63) == 0) red[tid >> 6] = m;
    __syncthreads();
    float mm = fmaxf(fmaxf(red[0], red[1]), fmaxf(red[2], red[3]));
    float e0 = expf(x.x - mm), e1 = expf(x.y - mm);
    float e2 = expf(x.z - mm), e3 = expf(x.w - mm);
    float s = e0 + e1 + e2 + e3;
#pragma unroll
    for (int off = 32; off; off >>= 1) s += __shfl_xor(s, off);
    __shared__ float red2[4];
    if ((tid & 63) == 0) red2[tid >> 6] = s;
    __syncthreads();
    float inv = 1.0f / (red2[0] + red2[1] + red2[2] + red2[3]);
    a4[tid] = make_float4(e0 * inv, e1 * inv, e2 * inv, e3 * inv);
}

// ---------------------------------------------------------------------------
// DPP cross-lane helpers (VALU-latency, no LDS pipe).
// ---------------------------------------------------------------------------
template<int CTRL>
__device__ __forceinline__ int dpp_i(int x) {
    return __builtin_amdgcn_update_dpp(0, x, CTRL, 0xF, 0xF, true);
}
__device__ __forceinline__ float wave_sum64(float x) {
    x += __int_as_float(dpp_i<0xB1>(__float_as_int(x)));
    x += __int_as_float(dpp_i<0x4E>(__float_as_int(x)));
    x += __int_as_float(dpp_i<0x141>(__float_as_int(x)));
    x += __int_as_float(dpp_i<0x140>(__float_as_int(x)));
    int xi = __float_as_int(x);
    float a = __int_as_float(__builtin_amdgcn_readlane(xi, 0));
    float b = __int_as_float(__builtin_amdgcn_readlane(xi, 16));
    float c = __int_as_float(__builtin_amdgcn_readlane(xi, 32));
    float d = __int_as_float(__builtin_amdgcn_readlane(xi, 48));
    return (a + c) + (b + d);
}
__device__ __forceinline__ float wave_min64f(float x) {
    x = fminf(x, __int_as_float(dpp_i<0xB1>(__float_as_int(x))));
    x = fminf(x, __int_as_float(dpp_i<0x4E>(__float_as_int(x))));
    x = fminf(x, __int_as_float(dpp_i<0x141>(__float_as_int(x))));
    x = fminf(x, __int_as_float(dpp_i<0x140>(__float_as_int(x))));
    int xi = __float_as_int(x);
    float a = __int_as_float(__builtin_amdgcn_readlane(xi, 0));
    float b = __int_as_float(__builtin_amdgcn_readlane(xi, 16));
    float c = __int_as_float(__builtin_amdgcn_readlane(xi, 32));
    float d = __int_as_float(__builtin_amdgcn_readlane(xi, 48));
    return fminf(fminf(a, b), fminf(c, d));
}
__device__ __forceinline__ unsigned wave_min64u(unsigned x) {
    unsigned o;
    o = (unsigned)dpp_i<0xB1>((int)x);  x = (o < x) ? o : x;
    o = (unsigned)dpp_i<0x4E>((int)x);  x = (o < x) ? o : x;
    o = (unsigned)dpp_i<0x141>((int)x); x = (o < x) ? o : x;
    o = (unsigned)dpp_i<0x140>((int)x); x = (o < x) ? o : x;
    unsigned a = (unsigned)__builtin_amdgcn_readlane((int)x, 0);
    unsigned b = (unsigned)__builtin_amdgcn_readlane((int)x, 16);
    unsigned c = (unsigned)__builtin_amdgcn_readlane((int)x, 32);
    unsigned d = (unsigned)__builtin_amdgcn_readlane((int)x, 48);
    unsigned ab = (a < b) ? a : b, cd = (c < d) ? c : d;
    return (ab < cd) ? ab : cd;
}

// ---------------------------------------------------------------------------
// A2S sequential scan (v4 structure, unchanged).
// ---------------------------------------------------------------------------
__global__ __launch_bounds__(64) void scan_kernel4(const float* __restrict__ scores,
                                                   unsigned char* __restrict__ keep)
{
    int bh = blockIdx.x;
    int lane = threadIdx.x;
    const float4* A4 = (const float4*)(scores + (size_t)bh * Ss * Ss);
    unsigned char* KP = keep + (size_t)bh * Ss * Ss;
    const float INFv = __int_as_float(0x7f800000);

    float sel[4][4] = {};
    float4 r0[4], r1[4], r2[4], r3[4];

#define LOADROW(RB, ROW)                                                     \
    do {                                                                     \
        size_t _base = (size_t)(ROW) * 256 + lane;                           \
        RB[0] = A4[_base];       RB[1] = A4[_base + 64];                     \
        RB[2] = A4[_base + 128]; RB[3] = A4[_base + 192];                    \
    } while (0)

#define WARM_STEP(RB, NEXTROW)                                               \
    do {                                                                     \
        float4 _a[4];                                                        \
        _a[0] = RB[0]; _a[1] = RB[1]; _a[2] = RB[2]; _a[3] = RB[3];          \
        LOADROW(RB, NEXTROW);                                                \
        _Pragma("unroll")                                                    \
        for (int jj = 0; jj < 4; ++jj) {                                     \
            sel[jj][0] = fmaf(FFf, sel[jj][0], _a[jj].x);                    \
            sel[jj][1] = fmaf(FFf, sel[jj][1], _a[jj].y);                    \
            sel[jj][2] = fmaf(FFf, sel[jj][2], _a[jj].z);                    \
            sel[jj][3] = fmaf(FFf, sel[jj][3], _a[jj].w);                    \
        }                                                                    \
    } while (0)

    LOADROW(r0, 0); LOADROW(r1, 1); LOADROW(r2, 2); LOADROW(r3, 3);
    for (int r = 0; r < 160; r += 4) {
        WARM_STEP(r0, r + 4);
        WARM_STEP(r1, r + 5);
        WARM_STEP(r2, r + 6);
        WARM_STEP(r3, r + 7);
    }
    {
        float4 tl[3][4];
#pragma unroll
        for (int jj = 0; jj < 4; ++jj) { tl[0][jj] = r0[jj]; tl[1][jj] = r1[jj]; tl[2][jj] = r2[jj]; }
#pragma unroll
        for (int u = 0; u < 3; ++u)
#pragma unroll
            for (int jj = 0; jj < 4; ++jj) {
                sel[jj][0] = fmaf(FFf, sel[jj][0], tl[u][jj].x);
                sel[jj][1] = fmaf(FFf, sel[jj][1], tl[u][jj].y);
                sel[jj][2] = fmaf(FFf, sel[jj][2], tl[u][jj].z);
                sel[jj][3] = fmaf(FFf, sel[jj][3], tl[u][jj].w);
            }
    }

    unsigned int mbits = 0xFFFFu;

    LOADROW(r0, CBc);     LOADROW(r1, CBc + 1);
    LOADROW(r2, CBc + 2); LOADROW(r3, CBc + 3);

#define SCAN_STEP(RB, T)                                                     \
    do {                                                                     \
        const int _t = (T);                                                  \
        float cur[4][4];                                                     \
        float lsum = 0.0f;                                                   \
        _Pragma("unroll")                                                    \
        for (int jj = 0; jj < 4; ++jj) {                                     \
            cur[jj][0] = ((mbits >> (jj * 4 + 0)) & 1) ? RB[jj].x : 0.0f;    \
            cur[jj][1] = ((mbits >> (jj * 4 + 1)) & 1) ? RB[jj].y : 0.0f;    \
            cur[jj][2] = ((mbits >> (jj * 4 + 2)) & 1) ? RB[jj].z : 0.0f;    \
            cur[jj][3] = ((mbits >> (jj * 4 + 3)) & 1) ? RB[jj].w : 0.0f;    \
            lsum += (cur[jj][0] + cur[jj][1]) + (cur[jj][2] + cur[jj][3]);   \
        }                                                                    \
        int _tp = _t + 4; if (_tp > Ss - 1) _tp = Ss - 1;                    \
        LOADROW(RB, _tp);                                                    \
        float tot = wave_sum64(lsum);                                        \
        float inv = 1.0f / tot;                                              \
        int local = _t - RBc;                                                \
        float cand[4][4];                                                    \
        _Pragma("unroll")                                                    \
        for (int jj = 0; jj < 4; ++jj) {                                     \
            _Pragma("unroll")                                                \
            for (int i = 0; i < 4; ++i) {                                    \
                float sv = fmaf(FFf, sel[jj][i], cur[jj][i] * inv);          \
                sel[jj][i] = sv;                                             \
                int s = jj * 256 + lane * 4 + i;                             \
                cand[jj][i] = (s >= SBc && s <= local) ? sv : INFv;          \
            }                                                                \
        }                                                                    \
        float m0 = fminf(fminf(cand[0][0], cand[0][1]), fminf(cand[0][2], cand[0][3])); \
        float m1 = fminf(fminf(cand[1][0], cand[1][1]), fminf(cand[1][2], cand[1][3])); \
        float m2 = fminf(fminf(cand[2][0], cand[2][1]), fminf(cand[2][2], cand[2][3])); \
        float m3 = fminf(fminf(cand[3][0], cand[3][1]), fminf(cand[3][2], cand[3][3])); \
        float minv = wave_min64f(fminf(fminf(m0, m1), fminf(m2, m3)));       \
        unsigned lidx = 0x7FFFFFFFu;                                         \
        _Pragma("unroll")                                                    \
        for (int jj = 0; jj < 4; ++jj)                                       \
            _Pragma("unroll")                                                \
            for (int i = 0; i < 4; ++i) {                                    \
                unsigned s = (unsigned)(jj * 256 + lane * 4 + i);            \
                unsigned c = (cand[jj][i] == minv) ? s : 0x7FFFFFFFu;        \
                lidx = (c < lidx) ? c : lidx;                                \
            }                                                                \
        int besti = (int)wave_min64u(lidx);                                  \
        _Pragma("unroll")                                                    \
        for (int jj = 0; jj < 4; ++jj)                                       \
            _Pragma("unroll")                                                \
            for (int i = 0; i < 4; ++i) {                                    \
                int s = jj * 256 + lane * 4 + i;                             \
                if (s == besti) { sel[jj][i] = INFv; mbits &= ~(1u << (jj * 4 + i)); } \
            }                                                                \
        uchar4* kp4 = (uchar4*)(KP + (size_t)(_t + 1) * Ss);                 \
        _Pragma("unroll")                                                    \
        for (int jj = 0; jj < 4; ++jj) {                                     \
            uchar4 kb;                                                       \
            kb.x = (unsigned char)((mbits >> (jj * 4 + 0)) & 1);             \
            kb.y = (unsigned char)((mbits >> (jj * 4 + 1)) & 1);             \
            kb.z = (unsigned char)((mbits >> (jj * 4 + 2)) & 1);             \
            kb.w = (unsigned char)((mbits >> (jj * 4 + 3)) & 1);             \
            kp4[jj * 64 + lane] = kb;                                        \
        }                                                                    \
    } while (0)

    for (int t0 = CBc; t0 <= Ss - 2; t0 += 4) {
        SCAN_STEP(r0, t0 + 0);
        SCAN_STEP(r1, t0 + 1);
        SCAN_STEP(r2, t0 + 2);
        SCAN_STEP(r3, t0 + 3);
    }
#undef SCAN_STEP
#undef WARM_STEP
#undef LOADROW
}

// ---------------------------------------------------------------------------
// Masked renormalization IN PLACE: probs = scores*keep / sum(scores*keep).
// ---------------------------------------------------------------------------
__global__ __launch_bounds__(256) void renorm_rows(float* __restrict__ scores,
                                                   const unsigned char* __restrict__ keep)
{
    int row = blockIdx.x;
    int r = row % Ss;
    float4* a4 = (float4*)(scores + (size_t)row * Ss);
    int tid = threadIdx.x;
    float4 x = a4[tid];
    if (r > CBc) {
        const uchar4* kp = (const uchar4*)(keep + (size_t)row * Ss);
        uchar4 kb = kp[tid];
        if (!kb.x) x.x = 0.0f;
        if (!kb.y) x.y = 0.0f;
        if (!kb.z) x.z = 0.0f;
        if (!kb.w) x.w = 0.0f;
    }
    float s = (x.x + x.y) + (x.z + x.w);
#pragma unroll
    for (int off = 32; off; off >>= 1) s += __shfl_xor(s, off);
    __shared__ float red2[4];
    if ((tid & 63) == 0) red2[tid >> 6] = s;
    __syncthreads();
    float inv = 1.0f / (red2[0] + red2[1] + red2[2] + red2[3]);
    a4[tid] = make_float4(x.x * inv, x.y * inv, x.z * inv, x.w * inv);
}

// ---------------------------------------------------------------------------
// ctx = probs @ v (fp32), writing bf16 ctxb in [b*S][HID] layout for wo GEMM.
// ---------------------------------------------------------------------------
__global__ __launch_bounds__(256) void pv_gemm(const float* __restrict__ probs,
                                               const float* __restrict__ v,
                                               unsigned short* __restrict__ ctxb)
{
    int bh = blockIdx.z;
    int b_ = bh / NHh, h_ = bh % NHh;
    const float* P = probs + (size_t)bh * Ss * Ss;
    const float* V = v     + (size_t)bh * Ss * HDd;
    int bm = blockIdx.y * 64, bn = blockIdx.x * 64;
    int tid = threadIdx.x, tx = tid & 15, ty = tid >> 4;
    __shared__ float As[16][65];
    __shared__ float Bs[16][64];
    float acc[4][4] = {};
    int kend = bm + 64;  // causal truncation
    for (int k0 = 0; k0 < kend; k0 += 16) {
#pragma unroll
        for (int l = 0; l < 4; ++l) {
            int idx = tid + l * 256;
            int r = idx >> 4, c = idx & 15;
            As[c][r] = P[(size_t)(bm + r) * Ss + k0 + c];
        }
#pragma unroll
        for (int l = 0; l < 4; ++l) {
            int idx = tid + l * 256;
            int r = idx >> 6, c = idx & 63;
            Bs[r][c] = V[(size_t)(k0 + r) * HDd + bn + c];
        }
        __syncthreads();
#pragma unroll
        for (int kk = 0; kk < 16; ++kk) {
            float a[4], b[4];
#pragma unroll
            for (int i = 0; i < 4; ++i) a[i] = As[kk][ty * 4 + i];
#pragma unroll
            for (int j = 0; j < 4; ++j) b[j] = Bs[kk][tx * 4 + j];
#pragma unroll
            for (int i = 0; i < 4; ++i)
#pragma unroll
                for (int j = 0; j < 4; ++j)
                    acc[i][j] = fmaf(a[i], b[j], acc[i][j]);
        }
        __syncthreads();
    }
#pragma unroll
    for (int i = 0; i < 4; ++i) {
        int sq = bm + ty * 4 + i;
#pragma unroll
        for (int j = 0; j < 4; ++j) {
            int d = bn + tx * 4 + j;
            ctxb[(size_t)(b_ * Ss + sq) * HIDd + h_ * HDd + d] = f2b(acc[i][j]);
        }
    }
}

// ---------------------------------------------------------------------------
extern "C" void kernel_launch(void* const* d_in, const int* in_sizes, int n_in,
                              void* d_out, int out_size, void* d_ws, size_t ws_size,
                              hipStream_t stream)
{
    const float* hs = (const float*)d_in[0];
    const float* wq = (const float*)d_in[1];
    const float* wk = (const float*)d_in[2];
    const float* wv = (const float*)d_in[3];
    const float* wo = (const float*)d_in[4];
    float* out = (float*)d_out;

    float* ws = (float*)d_ws;
    size_t off = 0;
    float* qf   = ws + off; off += (size_t)NBH * Ss * HDd;   // 16 MB (reused: ctxb)
    float* kf   = ws + off; off += (size_t)NBH * Ss * HDd;   // 16 MB
    float* vf   = ws + off; off += (size_t)NBH * Ss * HDd;   // 16 MB
    float* attn = ws + off; off += (size_t)NBH * Ss * Ss;    // 128 MB
    unsigned char* keep = (unsigned char*)(ws + off); off += (size_t)NBH * Ss * Ss / 4; // 32 MB
    unsigned short* wot = (unsigned short*)(ws + off); off += (size_t)HIDd * HIDd / 2;  // 8 MB

    // Transients overlaid on attn (dead before attn is written). 8 MB = 2M floats each.
    unsigned short* hsh  = (unsigned short*)(attn);
    unsigned short* hsl  = (unsigned short*)(attn + 2u * 1024 * 1024);
    unsigned short* wqth = (unsigned short*)(attn + 4u * 1024 * 1024);
    unsigned short* wqtl = (unsigned short*)(attn + 6u * 1024 * 1024);
    unsigned short* wkth = (unsigned short*)(attn + 8u * 1024 * 1024);
    unsigned short* wktl = (unsigned short*)(attn + 10u * 1024 * 1024);
    unsigned short* wvt  = (unsigned short*)(attn + 12u * 1024 * 1024);
    // q/k split bf16 overlaid on keep (keep written only by the scan, later):
    unsigned short* qh = (unsigned short*)keep;
    unsigned short* ql = (unsigned short*)(keep + 8u * 1024 * 1024);
    unsigned short* kh = (unsigned short*)(keep + 16u * 1024 * 1024);
    unsigned short* kl = (unsigned short*)(keep + 24u * 1024 * 1024);
    // ctxb overlays qf (qf dead after rope):
    unsigned short* ctxb = (unsigned short*)qf;

    dim3 blk(256);
    const int M = Bb * Ss;  // 2048

    // hs -> split bf16
    conv_split<<<dim3((M * HIDd / 4 + 255) / 256), blk, 0, stream>>>(hs, hsh, hsl, M * HIDd / 4);

    // weight transposes
    dim3 gt(HIDd / 64, HIDd / 64);
    tconv_split<<<gt, blk, 0, stream>>>(wq, wqth, wqtl, HIDd, HIDd);
    tconv_split<<<gt, blk, 0, stream>>>(wk, wkth, wktl, HIDd, HIDd);
    tconv<<<gt, blk, 0, stream>>>(wv, wvt, HIDd, HIDd);
    tconv<<<gt, blk, 0, stream>>>(wo, wot, HIDd, HIDd);

    // projections: q,k split-precision MFMA; v single bf16 MFMA
    dim3 gp(HIDd / 128, M / 128);   // 16 x 16
    gemm_split<1><<<gp, blk, 0, stream>>>(hsh, hsl, wqth, wqtl, qf, M, HIDd, HIDd);
    gemm_split<1><<<gp, blk, 0, stream>>>(hsh, hsl, wkth, wktl, kf, M, HIDd, HIDd);
    gemm_bf16t<1><<<gp, blk, 0, stream>>>(hsh, wvt, vf, M, HIDd, HIDd);

    // RoPE (fp32 math) -> split bf16 q,k
    rope_qk_split<<<dim3(NBH * Ss), dim3(64), 0, stream>>>(qf, kf, qh, ql, kh, kl);

    // QK^T (split-precision MFMA) + causal mask
    attn_qk_split<<<dim3(Ss / 128, Ss / 128, NBH), blk, 0, stream>>>(qh, ql, kh, kl, attn);

    // attn -> normalized scores, in place
    softmax_rows<<<dim3(NROWS), blk, 0, stream>>>(attn);

    // sequential A2S scan -> keep mask (overwrites qh..kl region, now dead)
    scan_kernel4<<<dim3(NBH), dim3(64), 0, stream>>>(attn, keep);

    // scores -> final probs (keep-mask + renormalize), in place
    renorm_rows<<<dim3(NROWS), blk, 0, stream>>>(attn, keep);

    // ctx = probs @ v (fp32 math, bf16 out)
    pv_gemm<<<dim3(HDd / 64, Ss / 64, NBH), blk, 0, stream>>>(attn, vf, ctxb);

    // out = ctx @ wo (bf16 MFMA, fp32 out)
    gemm_bf16t<0><<<gp, blk, 0, stream>>>(ctxb, wot, out, M, HIDd, HIDd);
}